// Round 8
// baseline (716.613 us; speedup 1.0000x reference)
//
#include <hip/hip_runtime.h>
#include <hip/hip_fp16.h>

#define N_NODES 50000
#define F0 256
#define F1 128
#define F2 64
#define BN_EPS 1e-5f

typedef float f32x4 __attribute__((ext_vector_type(4)));
typedef __bf16 bf16x8 __attribute__((ext_vector_type(8)));
typedef unsigned short ushort8v __attribute__((ext_vector_type(8)));

__device__ __forceinline__ float bflo(unsigned v) { return __uint_as_float(v << 16); }
__device__ __forceinline__ float bfhi(unsigned v) { return __uint_as_float(v & 0xFFFF0000u); }
__device__ __forceinline__ unsigned short f2bf(float f) {
  unsigned u = __float_as_uint(f);
  u += 0x7FFFu + ((u >> 16) & 1u);
  return (unsigned short)(u >> 16);
}
__device__ __forceinline__ void split2(float a, unsigned short& hi, unsigned short& lo) {
  hi = f2bf(a);
  float hf = __uint_as_float((unsigned)hi << 16);
  lo = f2bf(a - hf);
}
__device__ __forceinline__ int rdl(int v, int l) { return __builtin_amdgcn_readlane(v, l); }
__device__ __forceinline__ float h2f(unsigned short h) {
  __half hh = *reinterpret_cast<__half*>(&h);
  return __half2float(hh);
}
__device__ __forceinline__ unsigned short f2h(float f) {
  __half hh = __float2half(f);
  return *reinterpret_cast<unsigned short*>(&hh);
}

// ---------------- CSR build ----------------
__global__ void count_dst(const int* __restrict__ dst, int* __restrict__ counts,
                          int* __restrict__ eslot, int E) {
  int e = blockIdx.x * blockDim.x + threadIdx.x;
  if (e < E) eslot[e] = atomicAdd(&counts[dst[e]], 1);
}

__global__ __launch_bounds__(256) void scan_blocks(const int* __restrict__ counts,
                                                   int* __restrict__ offs,
                                                   int* __restrict__ bsum,
                                                   float* __restrict__ dinv) {
  __shared__ int s_w[4];
  const int tid = threadIdx.x, lane = tid & 63, wid = tid >> 6;
  const int base = blockIdx.x * 1024 + tid * 4;
  int v0 = 0, v1 = 0, v2 = 0, v3 = 0;
  if (base + 3 < N_NODES) {
    int4 v = *(const int4*)(counts + base);
    v0 = v.x; v1 = v.y; v2 = v.z; v3 = v.w;
  } else if (base < N_NODES) {
    v0 = counts[base];
    if (base + 1 < N_NODES) v1 = counts[base + 1];
    if (base + 2 < N_NODES) v2 = counts[base + 2];
  }
  if (base < N_NODES) {
    dinv[base] = rsqrtf((float)v0 + 1.0f);
    if (base + 1 < N_NODES) dinv[base + 1] = rsqrtf((float)v1 + 1.0f);
    if (base + 2 < N_NODES) dinv[base + 2] = rsqrtf((float)v2 + 1.0f);
    if (base + 3 < N_NODES) dinv[base + 3] = rsqrtf((float)v3 + 1.0f);
  }
  int t = v0 + v1 + v2 + v3;
  int incl = t;
#pragma unroll
  for (int d = 1; d < 64; d <<= 1) {
    int x = __shfl_up(incl, d);
    if (lane >= d) incl += x;
  }
  if (lane == 63) s_w[wid] = incl;
  __syncthreads();
  int woff = 0;
#pragma unroll
  for (int j = 0; j < 4; j++)
    if (j < wid) woff += s_w[j];
  int p = woff + incl - t;
  if (base < N_NODES) offs[base] = p;
  p += v0;
  if (base + 1 < N_NODES) offs[base + 1] = p;
  p += v1;
  if (base + 2 < N_NODES) offs[base + 2] = p;
  p += v2;
  if (base + 3 < N_NODES) offs[base + 3] = p;
  if (tid == 255) bsum[blockIdx.x] = woff + incl;
}

__global__ void scan_tops(int* __restrict__ bsum, int* __restrict__ offs, int nblk) {
  int lane = threadIdx.x;
  int v = (lane < nblk) ? bsum[lane] : 0;
  int incl = v;
#pragma unroll
  for (int d = 1; d < 64; d <<= 1) {
    int x = __shfl_up(incl, d);
    if (lane >= d) incl += x;
  }
  if (lane < nblk) bsum[lane] = incl - v;
  if (lane == 63) offs[N_NODES] = incl;
}

__global__ __launch_bounds__(256) void scan_add(int* __restrict__ offs,
                                                const int* __restrict__ bsum) {
  const int add = bsum[blockIdx.x];
  const int base = blockIdx.x * 1024 + threadIdx.x * 4;
  if (base + 3 < N_NODES) {
    int4 v = *(const int4*)(offs + base);
    v.x += add; v.y += add; v.z += add; v.w += add;
    *(int4*)(offs + base) = v;
  } else if (base < N_NODES) {
    offs[base] += add;
    if (base + 1 < N_NODES) offs[base + 1] += add;
    if (base + 2 < N_NODES) offs[base + 2] += add;
  }
}

// pure gather->scatter: 4B packed entry {src:16, fp16(dinv[src]):16}
__global__ void fill_csr(const int* __restrict__ src, const int* __restrict__ dst,
                         const int* __restrict__ offs, const int* __restrict__ eslot,
                         const float* __restrict__ dinv,
                         unsigned* __restrict__ csrU, int E) {
  int e = blockIdx.x * blockDim.x + threadIdx.x;
  if (e < E) {
    int s = src[e], d = dst[e];
    int p = offs[d] + eslot[e];
    unsigned ent = (unsigned)s | ((unsigned)f2h(dinv[s]) << 16);
    __builtin_nontemporal_store(ent, &csrU[p]);
  }
}

__global__ void compute_rowsum(const int* __restrict__ offs,
                               const unsigned* __restrict__ csrU,
                               const float* __restrict__ dinv, float* __restrict__ rowsum) {
  int i = blockIdx.x * blockDim.x + threadIdx.x;
  if (i < N_NODES) {
    float di = dinv[i];
    float s = di;
    int e1 = offs[i + 1];
    for (int e = offs[i]; e < e1; e++) s += h2f((unsigned short)(csrU[e] >> 16));
    rowsum[i] = di * s;
  }
}

// ---------------- merged weight conversion: W[K][N] fp32 -> hi/lo [N][K] bf16 ----------------
__device__ __forceinline__ void wt_one(const float* W, unsigned short* Wh, unsigned short* Wl,
                                       int K, int N, int idx) {
  int k = idx / N, n = idx - k * N;
  unsigned short h, l;
  split2(W[idx], h, l);
  Wh[(size_t)n * K + k] = h;
  Wl[(size_t)n * K + k] = l;
}

__global__ void convert_weights(const float* __restrict__ We1, const float* __restrict__ We2,
                                const float* __restrict__ Wd1, const float* __restrict__ Wd2,
                                unsigned short* W1h, unsigned short* W1l,
                                unsigned short* W2h, unsigned short* W2l,
                                unsigned short* W3h, unsigned short* W3l,
                                unsigned short* W4h, unsigned short* W4l) {
  int idx = blockIdx.x * blockDim.x + threadIdx.x;
  if (idx < 32768) {
    wt_one(We1, W1h, W1l, 256, 128, idx);
  } else if (idx < 40960) {
    wt_one(We2, W2h, W2l, 128, 64, idx - 32768);
  } else if (idx < 49152) {
    wt_one(Wd1, W3h, W3l, 64, 128, idx - 40960);
  } else if (idx < 81920) {
    wt_one(Wd2, W4h, W4l, 128, 256, idx - 49152);
  }
}

// ---------------- split-bf16 MFMA GEMM ----------------
template <int BN, bool STATS, bool AF32>
__global__ __launch_bounds__(256) void mfma_gemm_split(
    const unsigned short* __restrict__ Ahi, const unsigned short* __restrict__ Alo,
    const float* __restrict__ Af,
    const unsigned short* __restrict__ Whi, const unsigned short* __restrict__ Wlo,
    const float* __restrict__ bias, const float* __restrict__ rowsum,
    unsigned short* __restrict__ Cb, float* __restrict__ Cf,
    float* __restrict__ stat, int M, int K, int N) {
  constexpr int BM = 128;
  constexpr int MT = (BN == 128) ? 4 : 2;
  constexpr int NT = 4;
  __shared__ __align__(16) unsigned short AsH[4][BM][8];
  __shared__ __align__(16) unsigned short AsL[4][BM][8];
  __shared__ __align__(16) unsigned short BsH[4][BN][8];
  __shared__ __align__(16) unsigned short BsL[4][BN][8];
  const int tid = threadIdx.x;
  const int lane = tid & 63, wid = tid >> 6;
  const int quad = lane >> 4, ln = lane & 15;
  const int m0 = blockIdx.x * BM;
  const int n0 = blockIdx.y * BN;
  const int wm = (BN == 128) ? (wid & 1) * 64 : wid * 32;
  const int wn = (BN == 128) ? (wid >> 1) * 64 : 0;
  f32x4 acc[MT][NT] = {};

  const int arow = tid >> 2, aseg = tid & 3;
  for (int k0 = 0; k0 < K; k0 += 32) {
#pragma unroll
    for (int i = 0; i < 2; i++) {
      int row = arow + i * 64;
      int gm = m0 + row;
      if (AF32) {
        float4 u0 = make_float4(0.f, 0.f, 0.f, 0.f), u1 = u0;
        if (gm < M) {
          u0 = *(const float4*)(Af + (size_t)gm * K + k0 + aseg * 8);
          u1 = *(const float4*)(Af + (size_t)gm * K + k0 + aseg * 8 + 4);
        }
        ushort4 h0, l0, h1, l1;
        split2(u0.x, h0.x, l0.x); split2(u0.y, h0.y, l0.y);
        split2(u0.z, h0.z, l0.z); split2(u0.w, h0.w, l0.w);
        split2(u1.x, h1.x, l1.x); split2(u1.y, h1.y, l1.y);
        split2(u1.z, h1.z, l1.z); split2(u1.w, h1.w, l1.w);
        *(ushort4*)(&AsH[aseg][row][0]) = h0;
        *(ushort4*)(&AsH[aseg][row][4]) = h1;
        *(ushort4*)(&AsL[aseg][row][0]) = l0;
        *(ushort4*)(&AsL[aseg][row][4]) = l1;
      } else {
        ushort8v vh = {0, 0, 0, 0, 0, 0, 0, 0};
        ushort8v vl = {0, 0, 0, 0, 0, 0, 0, 0};
        if (gm < M) {
          vh = *(const ushort8v*)(Ahi + (size_t)gm * K + k0 + aseg * 8);
          vl = *(const ushort8v*)(Alo + (size_t)gm * K + k0 + aseg * 8);
        }
        *(ushort8v*)(&AsH[aseg][row][0]) = vh;
        *(ushort8v*)(&AsL[aseg][row][0]) = vl;
      }
    }
#pragma unroll
    for (int i = 0; i < BN / 64; i++) {
      int n = arow + i * 64;
      *(ushort8v*)(&BsH[aseg][n][0]) =
          *(const ushort8v*)(Whi + (size_t)(n0 + n) * K + k0 + aseg * 8);
      *(ushort8v*)(&BsL[aseg][n][0]) =
          *(const ushort8v*)(Wlo + (size_t)(n0 + n) * K + k0 + aseg * 8);
    }
    __syncthreads();
    bf16x8 ah[MT], al[MT], bh[NT], bl[NT];
#pragma unroll
    for (int mt = 0; mt < MT; mt++) {
      ah[mt] = *(const bf16x8*)(&AsH[quad][wm + mt * 16 + ln][0]);
      al[mt] = *(const bf16x8*)(&AsL[quad][wm + mt * 16 + ln][0]);
    }
#pragma unroll
    for (int nt = 0; nt < NT; nt++) {
      bh[nt] = *(const bf16x8*)(&BsH[quad][wn + nt * 16 + ln][0]);
      bl[nt] = *(const bf16x8*)(&BsL[quad][wn + nt * 16 + ln][0]);
    }
#pragma unroll
    for (int mt = 0; mt < MT; mt++)
#pragma unroll
      for (int nt = 0; nt < NT; nt++) {
        acc[mt][nt] = __builtin_amdgcn_mfma_f32_16x16x32_bf16(ah[mt], bl[nt], acc[mt][nt], 0, 0, 0);
        acc[mt][nt] = __builtin_amdgcn_mfma_f32_16x16x32_bf16(al[mt], bh[nt], acc[mt][nt], 0, 0, 0);
        acc[mt][nt] = __builtin_amdgcn_mfma_f32_16x16x32_bf16(ah[mt], bh[nt], acc[mt][nt], 0, 0, 0);
      }
    __syncthreads();
  }

  if (!STATS) {
#pragma unroll
    for (int nt = 0; nt < NT; nt++) {
      int gn = n0 + wn + nt * 16 + ln;
      float bv = bias[gn];
#pragma unroll
      for (int mt = 0; mt < MT; mt++) {
#pragma unroll
        for (int r = 0; r < 4; r++) {
          int gm = m0 + wm + mt * 16 + quad * 4 + r;
          if (gm < M) Cb[(size_t)gm * N + gn] = f2bf(acc[mt][nt][r] + bv);
        }
      }
    }
  } else {
    float rs[MT][4];
#pragma unroll
    for (int mt = 0; mt < MT; mt++)
#pragma unroll
      for (int r = 0; r < 4; r++) {
        int gm = m0 + wm + mt * 16 + quad * 4 + r;
        rs[mt][r] = (gm < M) ? rowsum[gm] : 0.f;
      }
#pragma unroll
    for (int nt = 0; nt < NT; nt++) {
      int gn = n0 + wn + nt * 16 + ln;
      float bv = bias[gn];
      float ls = 0.f, lq = 0.f;
#pragma unroll
      for (int mt = 0; mt < MT; mt++) {
#pragma unroll
        for (int r = 0; r < 4; r++) {
          int gm = m0 + wm + mt * 16 + quad * 4 + r;
          if (gm < M) {
            float v = fmaxf(fmaf(bv, rs[mt][r], acc[mt][nt][r]), 0.f);
            Cf[(size_t)gm * N + gn] = v;
            ls += v;
            lq = fmaf(v, v, lq);
          }
        }
      }
      ls += __shfl_xor(ls, 16); ls += __shfl_xor(ls, 32);
      lq += __shfl_xor(lq, 16); lq += __shfl_xor(lq, 32);
      if (quad == 0) {
        atomicAdd(&stat[gn], ls);
        atomicAdd(&stat[256 + gn], lq);
      }
    }
  }
}

// ---------------- agg half-pass kernels ----------------
// Temporal feature-split: each dispatch processes a line-aligned half of the
// feature row, halving the per-XCD gather working set (L3->L2 latency).
// csr loads + outputs are nontemporal to protect hb L2 residency.

// 128-stride rows, 64-ch half (128B/edge): half-wave per edge, 2 edges/gather.
template <bool RELU_STATS, bool OUT_SPLIT>
__global__ __launch_bounds__(256) void agg128h(
    const unsigned short* __restrict__ hb, const int* __restrict__ offs,
    const unsigned* __restrict__ csrU, const float* __restrict__ dinv,
    float* __restrict__ outf, unsigned short* __restrict__ outhi,
    unsigned short* __restrict__ outlo, float* __restrict__ stat, int c0) {
  const int tid = threadIdx.x;
  const int lane = tid & 63;
  const int widx = tid >> 6;
  const int half = lane >> 5;
  const int hl = lane & 31;
  const int nwaves = gridDim.x * 4;
  const unsigned short* hbc = hb + c0;
  float ls0 = 0.f, ls1 = 0.f, lq0 = 0.f, lq1 = 0.f;

  for (int node = blockIdx.x * 4 + widx; node < N_NODES; node += nwaves) {
    const int e0 = __builtin_amdgcn_readfirstlane(offs[node]);
    const int e1 = __builtin_amdgcn_readfirstlane(offs[node + 1]);
    float a0 = 0.f, a1 = 0.f;
    for (int e = e0; e < e1; e += 64) {
      const int cnt = min(64, e1 - e);
      unsigned ent = 0;
      if (lane < cnt) ent = __builtin_nontemporal_load(&csrU[e + lane]);
      const int nb = (cnt + 15) & ~15;
      for (int j = 0; j < nb; j += 16) {
#pragma unroll
        for (int u = 0; u < 8; u++) {
          unsigned ca = (unsigned)rdl((int)ent, j + 2 * u);
          unsigned cb = (unsigned)rdl((int)ent, j + 2 * u + 1);
          unsigned ce = half ? cb : ca;
          int s = (int)(ce & 0xFFFFu);
          float w = h2f((unsigned short)(ce >> 16));
          unsigned v = *(const unsigned*)(hbc + (size_t)s * 128 + hl * 2);
          a0 = fmaf(bflo(v), w, a0);
          a1 = fmaf(bfhi(v), w, a1);
        }
      }
    }
    a0 += __shfl_xor(a0, 32);
    a1 += __shfl_xor(a1, 32);
    float di = dinv[node];
    unsigned vs = *(const unsigned*)(hbc + (size_t)node * 128 + hl * 2);
    a0 = fmaf(bflo(vs), di, a0) * di;
    a1 = fmaf(bfhi(vs), di, a1) * di;
    if (RELU_STATS) {
      a0 = fmaxf(a0, 0.f);
      a1 = fmaxf(a1, 0.f);
      if (half == 0) {
        ls0 += a0; ls1 += a1;
        lq0 = fmaf(a0, a0, lq0);
        lq1 = fmaf(a1, a1, lq1);
      }
    }
    if (half == 0) {
      size_t p = (size_t)node * 128 + c0 + hl * 2;
      if (OUT_SPLIT) {
        unsigned short h0, l0, h1, l1;
        split2(a0, h0, l0);
        split2(a1, h1, l1);
        __builtin_nontemporal_store((unsigned)h0 | ((unsigned)h1 << 16), (unsigned*)(outhi + p));
        __builtin_nontemporal_store((unsigned)l0 | ((unsigned)l1 << 16), (unsigned*)(outlo + p));
      } else {
        __builtin_nontemporal_store(a0, outf + p);
        __builtin_nontemporal_store(a1, outf + p + 1);
      }
    }
  }

  if (RELU_STATS) {
    __shared__ float red[4][64];
    if (half == 0) {
      red[widx][hl * 2 + 0] = ls0;
      red[widx][hl * 2 + 1] = ls1;
    }
    __syncthreads();
    if (tid < 64) {
      atomicAdd(&stat[c0 + tid], red[0][tid] + red[1][tid] + red[2][tid] + red[3][tid]);
    }
    __syncthreads();
    if (half == 0) {
      red[widx][hl * 2 + 0] = lq0;
      red[widx][hl * 2 + 1] = lq1;
    }
    __syncthreads();
    if (tid < 64) {
      atomicAdd(&stat[256 + c0 + tid], red[0][tid] + red[1][tid] + red[2][tid] + red[3][tid]);
    }
  }
}

// 64-stride rows, 32-ch half (64B = 1 line/edge): quarter-wave, 4 edges/gather.
template <bool RELU_STATS, bool OUT_SPLIT>
__global__ __launch_bounds__(256) void agg64h(
    const unsigned short* __restrict__ hb, const int* __restrict__ offs,
    const unsigned* __restrict__ csrU, const float* __restrict__ dinv,
    float* __restrict__ outf, unsigned short* __restrict__ outhi,
    unsigned short* __restrict__ outlo, float* __restrict__ stat, int c0) {
  const int tid = threadIdx.x;
  const int lane = tid & 63;
  const int widx = tid >> 6;
  const int q = lane >> 4;
  const int ql = lane & 15;
  const int nwaves = gridDim.x * 4;
  const unsigned short* hbc = hb + c0;
  float ls0 = 0.f, ls1 = 0.f, lq0 = 0.f, lq1 = 0.f;

  for (int node = blockIdx.x * 4 + widx; node < N_NODES; node += nwaves) {
    const int e0 = __builtin_amdgcn_readfirstlane(offs[node]);
    const int e1 = __builtin_amdgcn_readfirstlane(offs[node + 1]);
    float a0 = 0.f, a1 = 0.f;
    for (int e = e0; e < e1; e += 64) {
      const int cnt = min(64, e1 - e);
      unsigned ent = 0;
      if (lane < cnt) ent = __builtin_nontemporal_load(&csrU[e + lane]);
      const int nb = (cnt + 7) & ~7;
      for (int j = 0; j < nb; j += 8) {
#pragma unroll
        for (int u = 0; u < 2; u++) {
          int b = j + 4 * u;
          unsigned ea = (unsigned)rdl((int)ent, b + 0);
          unsigned eb = (unsigned)rdl((int)ent, b + 1);
          unsigned ec = (unsigned)rdl((int)ent, b + 2);
          unsigned ed = (unsigned)rdl((int)ent, b + 3);
          unsigned cx = (q & 1) ? eb : ea;
          unsigned cy = (q & 1) ? ed : ec;
          unsigned ce = (q & 2) ? cy : cx;
          int s = (int)(ce & 0xFFFFu);
          float w = h2f((unsigned short)(ce >> 16));
          unsigned v = *(const unsigned*)(hbc + (size_t)s * 64 + ql * 2);
          a0 = fmaf(bflo(v), w, a0);
          a1 = fmaf(bfhi(v), w, a1);
        }
      }
    }
    a0 += __shfl_xor(a0, 16); a0 += __shfl_xor(a0, 32);
    a1 += __shfl_xor(a1, 16); a1 += __shfl_xor(a1, 32);
    float di = dinv[node];
    unsigned vs = *(const unsigned*)(hbc + (size_t)node * 64 + ql * 2);
    a0 = fmaf(bflo(vs), di, a0) * di;
    a1 = fmaf(bfhi(vs), di, a1) * di;
    if (RELU_STATS) {
      a0 = fmaxf(a0, 0.f);
      a1 = fmaxf(a1, 0.f);
      if (q == 0) {
        ls0 += a0; ls1 += a1;
        lq0 = fmaf(a0, a0, lq0);
        lq1 = fmaf(a1, a1, lq1);
      }
    }
    if (q == 0) {
      size_t p = (size_t)node * 64 + c0 + ql * 2;
      if (OUT_SPLIT) {
        unsigned short h0, l0, h1, l1;
        split2(a0, h0, l0);
        split2(a1, h1, l1);
        __builtin_nontemporal_store((unsigned)h0 | ((unsigned)h1 << 16), (unsigned*)(outhi + p));
        __builtin_nontemporal_store((unsigned)l0 | ((unsigned)l1 << 16), (unsigned*)(outlo + p));
      } else {
        __builtin_nontemporal_store(a0, outf + p);
        __builtin_nontemporal_store(a1, outf + p + 1);
      }
    }
  }

  if (RELU_STATS) {
    __shared__ float red[4][32];
    if (q == 0) {
      red[widx][ql * 2 + 0] = ls0;
      red[widx][ql * 2 + 1] = ls1;
    }
    __syncthreads();
    if (tid < 32) {
      atomicAdd(&stat[c0 + tid], red[0][tid] + red[1][tid] + red[2][tid] + red[3][tid]);
    }
    __syncthreads();
    if (q == 0) {
      red[widx][ql * 2 + 0] = lq0;
      red[widx][ql * 2 + 1] = lq1;
    }
    __syncthreads();
    if (tid < 32) {
      atomicAdd(&stat[256 + c0 + tid], red[0][tid] + red[1][tid] + red[2][tid] + red[3][tid]);
    }
  }
}

// ---------------- BN apply with inline finalize ----------------
template <int F, bool RELU, bool WF32, bool WB16, bool WSPLIT>
__global__ __launch_bounds__(256) void bn_apply_f(const float* __restrict__ a,
                                                  const float* __restrict__ stat,
                                                  const float* __restrict__ g,
                                                  const float* __restrict__ bb,
                                                  float* __restrict__ outf,
                                                  unsigned short* __restrict__ outb,
                                                  unsigned short* __restrict__ outhi,
                                                  unsigned short* __restrict__ outlo) {
  __shared__ float s_scale[F], s_shift[F];
  const int tid = threadIdx.x;
  if (tid < F) {
    const float invN = 1.0f / (float)N_NODES;
    float mean = stat[tid] * invN;
    float var = fmaxf(stat[256 + tid] * invN - mean * mean, 0.f);
    float inv = rsqrtf(var + BN_EPS);
    float sc = g[tid] * inv;
    s_scale[tid] = sc;
    s_shift[tid] = bb[tid] - mean * sc;
  }
  __syncthreads();
  constexpr int C4 = F / 4;
  const int total = N_NODES * C4;
  for (int idx = blockIdx.x * blockDim.x + tid; idx < total; idx += gridDim.x * blockDim.x) {
    int c4 = idx % C4;
    float4 v = ((const float4*)a)[idx];
    float4 s = *(float4*)&s_scale[c4 * 4];
    float4 sh = *(float4*)&s_shift[c4 * 4];
    float4 o;
    o.x = fmaf(v.x, s.x, sh.x);
    o.y = fmaf(v.y, s.y, sh.y);
    o.z = fmaf(v.z, s.z, sh.z);
    o.w = fmaf(v.w, s.w, sh.w);
    if (RELU) {
      o.x = fmaxf(o.x, 0.f);
      o.y = fmaxf(o.y, 0.f);
      o.z = fmaxf(o.z, 0.f);
      o.w = fmaxf(o.w, 0.f);
    }
    if (WF32) ((float4*)outf)[idx] = o;
    if (WB16) {
      ushort4 b;
      b.x = f2bf(o.x); b.y = f2bf(o.y); b.z = f2bf(o.z); b.w = f2bf(o.w);
      ((ushort4*)outb)[idx] = b;
    }
    if (WSPLIT) {
      ushort4 h, l;
      split2(o.x, h.x, l.x);
      split2(o.y, h.y, l.y);
      split2(o.z, h.z, l.z);
      split2(o.w, h.w, l.w);
      ((ushort4*)outhi)[idx] = h;
      ((ushort4*)outlo)[idx] = l;
    }
  }
}

extern "C" void kernel_launch(void* const* d_in, const int* in_sizes, int n_in,
                              void* d_out, int out_size, void* d_ws, size_t ws_size,
                              hipStream_t stream) {
  const float* x = (const float*)d_in[0];
  const int* ei = (const int*)d_in[1];
  const int E = in_sizes[1] / 2;
  const int* src = ei;
  const int* dst = ei + E;
  const float* We1 = (const float*)d_in[2];  const float* be1 = (const float*)d_in[3];
  const float* g1  = (const float*)d_in[4];  const float* bb1 = (const float*)d_in[5];
  const float* We2 = (const float*)d_in[6];  const float* be2 = (const float*)d_in[7];
  const float* g2  = (const float*)d_in[8];  const float* bb2 = (const float*)d_in[9];
  const float* Wd1 = (const float*)d_in[10]; const float* bd1 = (const float*)d_in[11];
  const float* g3  = (const float*)d_in[12]; const float* bb3 = (const float*)d_in[13];
  const float* Wd2 = (const float*)d_in[14]; const float* bd2 = (const float*)d_in[15];
  const float* g4  = (const float*)d_in[16]; const float* bb4 = (const float*)d_in[17];

  float* out = (float*)d_out;
  char* ws = (char*)d_ws;
  // Region A [0, 48MB): disjoint lifetimes per step:
  unsigned short* A0b  = (unsigned short*)(ws + 0);         // L1 gemm out 128ch bf16
  unsigned short* A1b  = (unsigned short*)(ws + 12800000);  // L2 gemm out 64ch bf16
  unsigned short* C2b  = (unsigned short*)(ws + 32000000);  // enc2 bf16 (L3 agg input)
  unsigned short* G3hi = (unsigned short*)(ws + 0);         // L3 agg out hi (6.4M)
  unsigned short* G3lo = (unsigned short*)(ws + 6400000);   // L3 agg out lo (6.4M)
  unsigned short* D3b  = (unsigned short*)(ws + 12800000);  // h3 bf16 (L4 agg input, 12.8M)
  unsigned short* G4hi = (unsigned short*)(ws + 0);         // L4 agg out hi (12.8M)
  unsigned short* G4lo = (unsigned short*)(ws + 25600000);  // L4 agg out lo (12.8M)
  unsigned short* Wb   = (unsigned short*)(ws + 48000000);  // weights, persist
  unsigned short* W1h = Wb;            unsigned short* W1l = W1h + 32768;
  unsigned short* W2h = W1l + 32768;   unsigned short* W2l = W2h + 8192;
  unsigned short* W3h = W2l + 8192;    unsigned short* W3l = W3h + 8192;
  unsigned short* W4h = W3l + 8192;    unsigned short* W4l = W4h + 32768;
  float* B0f  = (float*)(ws + 51200000);  // pre-BN fp32 (up to 51.2M at L4)
  int*   eslot  = (int*)(ws + 51200000);     // 3.2M; dead before first B0f write (agg L1)
  unsigned* csrU = (unsigned*)(ws + 102400000);  // packed CSR 4B x E (3.2M)
  float* stat4  = (float*)(ws + 108800000);  // 4 x 512 floats
  int*   bsum   = (int*)(ws + 108808192);    // 64 ints for hierarchical scan
  int*   counts = (int*)(ws + 108810000);    // reused as rowsum after scan_blocks
  int*   offs   = (int*)(ws + 109210000);
  float* dinv   = (float*)(ws + 109410064);
  if (ws_size < 109604160) return;
  float* rowsum = (float*)counts;  // counts dead after scan_blocks

  float* enc1 = out + (size_t)N_NODES * F0;
  float* enc2 = enc1 + (size_t)N_NODES * F1;

  const int EB = (E + 255) / 256;
  const int AGG_GRID = 2048;
  const int MB = (N_NODES + 127) / 128;        // 391
  const int SCAN_B = (N_NODES + 1023) / 1024;  // 49

  // conversions + CSR build
  convert_weights<<<320, 256, 0, stream>>>(We1, We2, Wd1, Wd2, W1h, W1l, W2h, W2l,
                                           W3h, W3l, W4h, W4l);
  hipMemsetAsync(counts, 0, N_NODES * sizeof(int), stream);
  hipMemsetAsync(stat4, 0, 4 * 512 * sizeof(float), stream);
  count_dst<<<EB, 256, 0, stream>>>(dst, counts, eslot, E);
  scan_blocks<<<SCAN_B, 256, 0, stream>>>(counts, offs, bsum, dinv);
  scan_tops<<<1, 64, 0, stream>>>(bsum, offs, SCAN_B);
  scan_add<<<SCAN_B, 256, 0, stream>>>(offs, bsum);
  fill_csr<<<EB, 256, 0, stream>>>(src, dst, offs, eslot, dinv, csrU, E);
  compute_rowsum<<<(N_NODES + 255) / 256, 256, 0, stream>>>(offs, csrU, dinv, rowsum);

  // ---- Layer 1: F0 -> F1 (propagate after) ----
  mfma_gemm_split<128, false, true><<<dim3(MB, 1), 256, 0, stream>>>(
      nullptr, nullptr, x, W1h, W1l, be1, nullptr, A0b, nullptr, nullptr, N_NODES, F0, F1);
  agg128h<true, false><<<AGG_GRID, 256, 0, stream>>>(
      A0b, offs, csrU, dinv, B0f, nullptr, nullptr, stat4, 0);
  agg128h<true, false><<<AGG_GRID, 256, 0, stream>>>(
      A0b, offs, csrU, dinv, B0f, nullptr, nullptr, stat4, 64);
  bn_apply_f<F1, true, true, false, false><<<2048, 256, 0, stream>>>(
      B0f, stat4, g1, bb1, enc1, nullptr, nullptr, nullptr);

  // ---- Layer 2: F1 -> F2 (propagate after); GEMM reads enc1 fp32, splits in staging ----
  mfma_gemm_split<64, false, true><<<dim3(MB, 1), 256, 0, stream>>>(
      nullptr, nullptr, enc1, W2h, W2l, be2, nullptr, A1b, nullptr, nullptr, N_NODES, F1, F2);
  agg64h<true, false><<<AGG_GRID, 256, 0, stream>>>(
      A1b, offs, csrU, dinv, B0f, nullptr, nullptr, stat4 + 512, 0);
  agg64h<true, false><<<AGG_GRID, 256, 0, stream>>>(
      A1b, offs, csrU, dinv, B0f, nullptr, nullptr, stat4 + 512, 32);
  bn_apply_f<F2, false, true, true, false><<<2048, 256, 0, stream>>>(
      B0f, stat4 + 512, g2, bb2, enc2, C2b, nullptr, nullptr);

  // ---- Layer 3: F2 -> F1 (propagate FIRST) ----
  agg64h<false, true><<<AGG_GRID, 256, 0, stream>>>(
      C2b, offs, csrU, dinv, nullptr, G3hi, G3lo, nullptr, 0);
  agg64h<false, true><<<AGG_GRID, 256, 0, stream>>>(
      C2b, offs, csrU, dinv, nullptr, G3hi, G3lo, nullptr, 32);
  mfma_gemm_split<128, true, false><<<dim3(MB, 1), 256, 0, stream>>>(
      G3hi, G3lo, nullptr, W3h, W3l, bd1, rowsum, nullptr, B0f, stat4 + 1024, N_NODES, F2, F1);
  bn_apply_f<F1, true, false, true, false><<<2048, 256, 0, stream>>>(
      B0f, stat4 + 1024, g3, bb3, nullptr, D3b, nullptr, nullptr);

  // ---- Layer 4: F1 -> F0 (propagate FIRST) ----
  agg128h<false, true><<<AGG_GRID, 256, 0, stream>>>(
      D3b, offs, csrU, dinv, nullptr, G4hi, G4lo, nullptr, 0);
  agg128h<false, true><<<AGG_GRID, 256, 0, stream>>>(
      D3b, offs, csrU, dinv, nullptr, G4hi, G4lo, nullptr, 64);
  mfma_gemm_split<128, true, false><<<dim3(MB, 2), 256, 0, stream>>>(
      G4hi, G4lo, nullptr, W4h, W4l, bd2, rowsum, nullptr, B0f, stat4 + 1536, N_NODES, F1, F0);
  bn_apply_f<F0, false, true, false, false><<<2048, 256, 0, stream>>>(
      B0f, stat4 + 1536, g4, bb4, out, nullptr, nullptr, nullptr);
}

// Round 9
// 619.370 us; speedup vs baseline: 1.1570x; 1.1570x over previous
//
#include <hip/hip_runtime.h>
#include <hip/hip_fp16.h>

#define N_NODES 50000
#define F0 256
#define F1 128
#define F2 64
#define BN_EPS 1e-5f

typedef float f32x4 __attribute__((ext_vector_type(4)));
typedef __bf16 bf16x8 __attribute__((ext_vector_type(8)));
typedef unsigned short ushort8v __attribute__((ext_vector_type(8)));

__device__ __forceinline__ float bflo(unsigned v) { return __uint_as_float(v << 16); }
__device__ __forceinline__ float bfhi(unsigned v) { return __uint_as_float(v & 0xFFFF0000u); }
__device__ __forceinline__ unsigned short f2bf(float f) {
  unsigned u = __float_as_uint(f);
  u += 0x7FFFu + ((u >> 16) & 1u);
  return (unsigned short)(u >> 16);
}
__device__ __forceinline__ void split2(float a, unsigned short& hi, unsigned short& lo) {
  hi = f2bf(a);
  float hf = __uint_as_float((unsigned)hi << 16);
  lo = f2bf(a - hf);
}
__device__ __forceinline__ int rdl(int v, int l) { return __builtin_amdgcn_readlane(v, l); }
__device__ __forceinline__ float h2f(unsigned short h) {
  __half hh = *reinterpret_cast<__half*>(&h);
  return __half2float(hh);
}
__device__ __forceinline__ unsigned short f2h(float f) {
  __half hh = __float2half(f);
  return *reinterpret_cast<unsigned short*>(&hh);
}

// ---------------- CSR build ----------------
__global__ void count_dst(const int* __restrict__ dst, int* __restrict__ counts,
                          int* __restrict__ eslot, int E) {
  int e = blockIdx.x * blockDim.x + threadIdx.x;
  if (e < E) eslot[e] = atomicAdd(&counts[dst[e]], 1);
}

__global__ __launch_bounds__(256) void scan_blocks(const int* __restrict__ counts,
                                                   int* __restrict__ offs,
                                                   int* __restrict__ bsum,
                                                   float* __restrict__ dinv) {
  __shared__ int s_w[4];
  const int tid = threadIdx.x, lane = tid & 63, wid = tid >> 6;
  const int base = blockIdx.x * 1024 + tid * 4;
  int v0 = 0, v1 = 0, v2 = 0, v3 = 0;
  if (base + 3 < N_NODES) {
    int4 v = *(const int4*)(counts + base);
    v0 = v.x; v1 = v.y; v2 = v.z; v3 = v.w;
  } else if (base < N_NODES) {
    v0 = counts[base];
    if (base + 1 < N_NODES) v1 = counts[base + 1];
    if (base + 2 < N_NODES) v2 = counts[base + 2];
  }
  if (base < N_NODES) {
    dinv[base] = rsqrtf((float)v0 + 1.0f);
    if (base + 1 < N_NODES) dinv[base + 1] = rsqrtf((float)v1 + 1.0f);
    if (base + 2 < N_NODES) dinv[base + 2] = rsqrtf((float)v2 + 1.0f);
    if (base + 3 < N_NODES) dinv[base + 3] = rsqrtf((float)v3 + 1.0f);
  }
  int t = v0 + v1 + v2 + v3;
  int incl = t;
#pragma unroll
  for (int d = 1; d < 64; d <<= 1) {
    int x = __shfl_up(incl, d);
    if (lane >= d) incl += x;
  }
  if (lane == 63) s_w[wid] = incl;
  __syncthreads();
  int woff = 0;
#pragma unroll
  for (int j = 0; j < 4; j++)
    if (j < wid) woff += s_w[j];
  int p = woff + incl - t;
  if (base < N_NODES) offs[base] = p;
  p += v0;
  if (base + 1 < N_NODES) offs[base + 1] = p;
  p += v1;
  if (base + 2 < N_NODES) offs[base + 2] = p;
  p += v2;
  if (base + 3 < N_NODES) offs[base + 3] = p;
  if (tid == 255) bsum[blockIdx.x] = woff + incl;
}

__global__ void scan_tops(int* __restrict__ bsum, int* __restrict__ offs, int nblk) {
  int lane = threadIdx.x;
  int v = (lane < nblk) ? bsum[lane] : 0;
  int incl = v;
#pragma unroll
  for (int d = 1; d < 64; d <<= 1) {
    int x = __shfl_up(incl, d);
    if (lane >= d) incl += x;
  }
  if (lane < nblk) bsum[lane] = incl - v;
  if (lane == 63) offs[N_NODES] = incl;
}

__global__ __launch_bounds__(256) void scan_add(int* __restrict__ offs,
                                                const int* __restrict__ bsum) {
  const int add = bsum[blockIdx.x];
  const int base = blockIdx.x * 1024 + threadIdx.x * 4;
  if (base + 3 < N_NODES) {
    int4 v = *(const int4*)(offs + base);
    v.x += add; v.y += add; v.z += add; v.w += add;
    *(int4*)(offs + base) = v;
  } else if (base < N_NODES) {
    offs[base] += add;
    if (base + 1 < N_NODES) offs[base + 1] += add;
    if (base + 2 < N_NODES) offs[base + 2] += add;
  }
}

// pure gather->scatter: 4B packed entry {src:16, fp16(dinv[src]):16}
__global__ void fill_csr(const int* __restrict__ src, const int* __restrict__ dst,
                         const int* __restrict__ offs, const int* __restrict__ eslot,
                         const float* __restrict__ dinv,
                         unsigned* __restrict__ csrU, int E) {
  int e = blockIdx.x * blockDim.x + threadIdx.x;
  if (e < E) {
    int s = src[e], d = dst[e];
    int p = offs[d] + eslot[e];
    unsigned ent = (unsigned)s | ((unsigned)f2h(dinv[s]) << 16);
    __builtin_nontemporal_store(ent, &csrU[p]);
  }
}

__global__ void compute_rowsum(const int* __restrict__ offs,
                               const unsigned* __restrict__ csrU,
                               const float* __restrict__ dinv, float* __restrict__ rowsum) {
  int i = blockIdx.x * blockDim.x + threadIdx.x;
  if (i < N_NODES) {
    float di = dinv[i];
    float s = di;
    int e1 = offs[i + 1];
    for (int e = offs[i]; e < e1; e++) s += h2f((unsigned short)(csrU[e] >> 16));
    rowsum[i] = di * s;
  }
}

// ---------------- merged weight conversion: W[K][N] fp32 -> hi/lo [N][K] bf16 ----------------
__device__ __forceinline__ void wt_one(const float* W, unsigned short* Wh, unsigned short* Wl,
                                       int K, int N, int idx) {
  int k = idx / N, n = idx - k * N;
  unsigned short h, l;
  split2(W[idx], h, l);
  Wh[(size_t)n * K + k] = h;
  Wl[(size_t)n * K + k] = l;
}

__global__ void convert_weights(const float* __restrict__ We1, const float* __restrict__ We2,
                                const float* __restrict__ Wd1, const float* __restrict__ Wd2,
                                unsigned short* W1h, unsigned short* W1l,
                                unsigned short* W2h, unsigned short* W2l,
                                unsigned short* W3h, unsigned short* W3l,
                                unsigned short* W4h, unsigned short* W4l) {
  int idx = blockIdx.x * blockDim.x + threadIdx.x;
  if (idx < 32768) {
    wt_one(We1, W1h, W1l, 256, 128, idx);
  } else if (idx < 40960) {
    wt_one(We2, W2h, W2l, 128, 64, idx - 32768);
  } else if (idx < 49152) {
    wt_one(Wd1, W3h, W3l, 64, 128, idx - 40960);
  } else if (idx < 81920) {
    wt_one(Wd2, W4h, W4l, 128, 256, idx - 49152);
  }
}

// ---------------- split-bf16 MFMA GEMM, 8-wave blocks ----------------
// 512 threads: A staged one-row-per-thread; waves tile 4x2 (BN=128) or 8x1 (BN=64).
template <int BN, bool STATS, bool AF32>
__global__ __launch_bounds__(512) void mfma_gemm_split(
    const unsigned short* __restrict__ Ahi, const unsigned short* __restrict__ Alo,
    const float* __restrict__ Af,
    const unsigned short* __restrict__ Whi, const unsigned short* __restrict__ Wlo,
    const float* __restrict__ bias, const float* __restrict__ rowsum,
    unsigned short* __restrict__ Cb, float* __restrict__ Cf,
    float* __restrict__ stat, int M, int K, int N) {
  constexpr int BM = 128;
  constexpr int MT = (BN == 128) ? 2 : 1;
  constexpr int NT = 4;
  __shared__ __align__(16) unsigned short AsH[4][BM][8];
  __shared__ __align__(16) unsigned short AsL[4][BM][8];
  __shared__ __align__(16) unsigned short BsH[4][BN][8];
  __shared__ __align__(16) unsigned short BsL[4][BN][8];
  const int tid = threadIdx.x;
  const int lane = tid & 63, wid = tid >> 6;  // wid 0..7
  const int quad = lane >> 4, ln = lane & 15;
  const int m0 = blockIdx.x * BM;
  const int n0 = blockIdx.y * BN;
  const int wm = (BN == 128) ? (wid & 3) * 32 : wid * 16;
  const int wn = (BN == 128) ? (wid >> 2) * 64 : 0;
  f32x4 acc[MT][NT] = {};

  const int arow = tid >> 2, aseg = tid & 3;  // arow 0..127
  for (int k0 = 0; k0 < K; k0 += 32) {
    {
      int gm = m0 + arow;
      if (AF32) {
        float4 u0 = make_float4(0.f, 0.f, 0.f, 0.f), u1 = u0;
        if (gm < M) {
          u0 = *(const float4*)(Af + (size_t)gm * K + k0 + aseg * 8);
          u1 = *(const float4*)(Af + (size_t)gm * K + k0 + aseg * 8 + 4);
        }
        ushort4 h0, l0, h1, l1;
        split2(u0.x, h0.x, l0.x); split2(u0.y, h0.y, l0.y);
        split2(u0.z, h0.z, l0.z); split2(u0.w, h0.w, l0.w);
        split2(u1.x, h1.x, l1.x); split2(u1.y, h1.y, l1.y);
        split2(u1.z, h1.z, l1.z); split2(u1.w, h1.w, l1.w);
        *(ushort4*)(&AsH[aseg][arow][0]) = h0;
        *(ushort4*)(&AsH[aseg][arow][4]) = h1;
        *(ushort4*)(&AsL[aseg][arow][0]) = l0;
        *(ushort4*)(&AsL[aseg][arow][4]) = l1;
      } else {
        ushort8v vh = {0, 0, 0, 0, 0, 0, 0, 0};
        ushort8v vl = {0, 0, 0, 0, 0, 0, 0, 0};
        if (gm < M) {
          vh = *(const ushort8v*)(Ahi + (size_t)gm * K + k0 + aseg * 8);
          vl = *(const ushort8v*)(Alo + (size_t)gm * K + k0 + aseg * 8);
        }
        *(ushort8v*)(&AsH[aseg][arow][0]) = vh;
        *(ushort8v*)(&AsL[aseg][arow][0]) = vl;
      }
    }
    if (BN == 128 || arow < BN) {
      int n = arow;
      *(ushort8v*)(&BsH[aseg][n][0]) =
          *(const ushort8v*)(Whi + (size_t)(n0 + n) * K + k0 + aseg * 8);
      *(ushort8v*)(&BsL[aseg][n][0]) =
          *(const ushort8v*)(Wlo + (size_t)(n0 + n) * K + k0 + aseg * 8);
    }
    __syncthreads();
    bf16x8 ah[MT], al[MT], bh[NT], bl[NT];
#pragma unroll
    for (int mt = 0; mt < MT; mt++) {
      ah[mt] = *(const bf16x8*)(&AsH[quad][wm + mt * 16 + ln][0]);
      al[mt] = *(const bf16x8*)(&AsL[quad][wm + mt * 16 + ln][0]);
    }
#pragma unroll
    for (int nt = 0; nt < NT; nt++) {
      bh[nt] = *(const bf16x8*)(&BsH[quad][wn + nt * 16 + ln][0]);
      bl[nt] = *(const bf16x8*)(&BsL[quad][wn + nt * 16 + ln][0]);
    }
#pragma unroll
    for (int mt = 0; mt < MT; mt++)
#pragma unroll
      for (int nt = 0; nt < NT; nt++) {
        acc[mt][nt] = __builtin_amdgcn_mfma_f32_16x16x32_bf16(ah[mt], bl[nt], acc[mt][nt], 0, 0, 0);
        acc[mt][nt] = __builtin_amdgcn_mfma_f32_16x16x32_bf16(al[mt], bh[nt], acc[mt][nt], 0, 0, 0);
        acc[mt][nt] = __builtin_amdgcn_mfma_f32_16x16x32_bf16(ah[mt], bh[nt], acc[mt][nt], 0, 0, 0);
      }
    __syncthreads();
  }

  if (!STATS) {
#pragma unroll
    for (int nt = 0; nt < NT; nt++) {
      int gn = n0 + wn + nt * 16 + ln;
      float bv = bias[gn];
#pragma unroll
      for (int mt = 0; mt < MT; mt++) {
#pragma unroll
        for (int r = 0; r < 4; r++) {
          int gm = m0 + wm + mt * 16 + quad * 4 + r;
          if (gm < M) Cb[(size_t)gm * N + gn] = f2bf(acc[mt][nt][r] + bv);
        }
      }
    }
  } else {
    float rs[MT][4];
#pragma unroll
    for (int mt = 0; mt < MT; mt++)
#pragma unroll
      for (int r = 0; r < 4; r++) {
        int gm = m0 + wm + mt * 16 + quad * 4 + r;
        rs[mt][r] = (gm < M) ? rowsum[gm] : 0.f;
      }
#pragma unroll
    for (int nt = 0; nt < NT; nt++) {
      int gn = n0 + wn + nt * 16 + ln;
      float bv = bias[gn];
      float ls = 0.f, lq = 0.f;
#pragma unroll
      for (int mt = 0; mt < MT; mt++) {
#pragma unroll
        for (int r = 0; r < 4; r++) {
          int gm = m0 + wm + mt * 16 + quad * 4 + r;
          if (gm < M) {
            float v = fmaxf(fmaf(bv, rs[mt][r], acc[mt][nt][r]), 0.f);
            Cf[(size_t)gm * N + gn] = v;
            ls += v;
            lq = fmaf(v, v, lq);
          }
        }
      }
      ls += __shfl_xor(ls, 16); ls += __shfl_xor(ls, 32);
      lq += __shfl_xor(lq, 16); lq += __shfl_xor(lq, 32);
      if (quad == 0) {
        atomicAdd(&stat[gn], ls);
        atomicAdd(&stat[256 + gn], lq);
      }
    }
  }
}

// ---------------- agg F=128, packed-u32 readlane broadcast, one node per wave ----------------
template <bool RELU_STATS, bool OUT_SPLIT>
__global__ __launch_bounds__(256) void agg128_rl(
    const unsigned short* __restrict__ hb, const int* __restrict__ offs,
    const unsigned* __restrict__ csrU, const float* __restrict__ dinv,
    float* __restrict__ outf, unsigned short* __restrict__ outhi,
    unsigned short* __restrict__ outlo, float* __restrict__ stat) {
  const int tid = threadIdx.x;
  const int lane = tid & 63;
  const int widx = tid >> 6;
  const int nwaves = gridDim.x * 4;
  float ls0 = 0.f, ls1 = 0.f, lq0 = 0.f, lq1 = 0.f;

  for (int node = blockIdx.x * 4 + widx; node < N_NODES; node += nwaves) {
    const int e0 = __builtin_amdgcn_readfirstlane(offs[node]);
    const int e1 = __builtin_amdgcn_readfirstlane(offs[node + 1]);
    float a0 = 0.f, a1 = 0.f;
    for (int e = e0; e < e1; e += 64) {
      const int cnt = min(64, e1 - e);
      unsigned ent = 0;
      if (lane < cnt) ent = csrU[e + lane];
      const int nb = (cnt + 7) & ~7;
      for (int j = 0; j < nb; j += 8) {
#pragma unroll
        for (int u = 0; u < 8; u++) {
          unsigned ce = (unsigned)rdl((int)ent, j + u);
          int s = (int)(ce & 0xFFFFu);
          float w = h2f((unsigned short)(ce >> 16));
          unsigned v = *(const unsigned*)(hb + (size_t)s * 128 + lane * 2);
          a0 = fmaf(bflo(v), w, a0);
          a1 = fmaf(bfhi(v), w, a1);
        }
      }
    }
    float di = dinv[node];
    unsigned vs = *(const unsigned*)(hb + (size_t)node * 128 + lane * 2);
    a0 = fmaf(bflo(vs), di, a0) * di;
    a1 = fmaf(bfhi(vs), di, a1) * di;
    if (RELU_STATS) {
      a0 = fmaxf(a0, 0.f);
      a1 = fmaxf(a1, 0.f);
      ls0 += a0; ls1 += a1;
      lq0 = fmaf(a0, a0, lq0);
      lq1 = fmaf(a1, a1, lq1);
    }
    if (OUT_SPLIT) {
      unsigned short h0, l0, h1, l1;
      split2(a0, h0, l0);
      split2(a1, h1, l1);
      *(unsigned*)(outhi + (size_t)node * 128 + lane * 2) = (unsigned)h0 | ((unsigned)h1 << 16);
      *(unsigned*)(outlo + (size_t)node * 128 + lane * 2) = (unsigned)l0 | ((unsigned)l1 << 16);
    } else {
      *(float2*)(outf + (size_t)node * 128 + lane * 2) = make_float2(a0, a1);
    }
  }

  if (RELU_STATS) {
    __shared__ float red[4][128];
    red[widx][lane * 2 + 0] = ls0;
    red[widx][lane * 2 + 1] = ls1;
    __syncthreads();
    if (tid < 128) {
      atomicAdd(&stat[tid], red[0][tid] + red[1][tid] + red[2][tid] + red[3][tid]);
    }
    __syncthreads();
    red[widx][lane * 2 + 0] = lq0;
    red[widx][lane * 2 + 1] = lq1;
    __syncthreads();
    if (tid < 128) {
      atomicAdd(&stat[256 + tid], red[0][tid] + red[1][tid] + red[2][tid] + red[3][tid]);
    }
  }
}

// ---------------- agg F=64, packed-u32 readlane broadcast, two edges per gather ----------------
template <bool RELU_STATS, bool OUT_SPLIT>
__global__ __launch_bounds__(256) void agg64_rl(
    const unsigned short* __restrict__ hb, const int* __restrict__ offs,
    const unsigned* __restrict__ csrU, const float* __restrict__ dinv,
    float* __restrict__ outf, unsigned short* __restrict__ outhi,
    unsigned short* __restrict__ outlo, float* __restrict__ stat) {
  const int tid = threadIdx.x;
  const int lane = tid & 63;
  const int widx = tid >> 6;
  const int half = lane >> 5;
  const int hl = lane & 31;
  const int nwaves = gridDim.x * 4;
  float ls0 = 0.f, ls1 = 0.f, lq0 = 0.f, lq1 = 0.f;

  for (int node = blockIdx.x * 4 + widx; node < N_NODES; node += nwaves) {
    const int e0 = __builtin_amdgcn_readfirstlane(offs[node]);
    const int e1 = __builtin_amdgcn_readfirstlane(offs[node + 1]);
    float a0 = 0.f, a1 = 0.f;
    for (int e = e0; e < e1; e += 64) {
      const int cnt = min(64, e1 - e);
      unsigned ent = 0;
      if (lane < cnt) ent = csrU[e + lane];
      const int nb = (cnt + 15) & ~15;
      for (int j = 0; j < nb; j += 16) {
#pragma unroll
        for (int u = 0; u < 8; u++) {
          unsigned ca = (unsigned)rdl((int)ent, j + 2 * u);
          unsigned cb = (unsigned)rdl((int)ent, j + 2 * u + 1);
          unsigned ce = half ? cb : ca;
          int s = (int)(ce & 0xFFFFu);
          float w = h2f((unsigned short)(ce >> 16));
          unsigned v = *(const unsigned*)(hb + (size_t)s * 64 + hl * 2);
          a0 = fmaf(bflo(v), w, a0);
          a1 = fmaf(bfhi(v), w, a1);
        }
      }
    }
    a0 += __shfl_xor(a0, 32);
    a1 += __shfl_xor(a1, 32);
    float di = dinv[node];
    unsigned vs = *(const unsigned*)(hb + (size_t)node * 64 + hl * 2);
    a0 = fmaf(bflo(vs), di, a0) * di;
    a1 = fmaf(bfhi(vs), di, a1) * di;
    if (RELU_STATS) {
      a0 = fmaxf(a0, 0.f);
      a1 = fmaxf(a1, 0.f);
      if (half == 0) {
        ls0 += a0; ls1 += a1;
        lq0 = fmaf(a0, a0, lq0);
        lq1 = fmaf(a1, a1, lq1);
      }
    }
    if (half == 0) {
      if (OUT_SPLIT) {
        unsigned short h0, l0, h1, l1;
        split2(a0, h0, l0);
        split2(a1, h1, l1);
        *(unsigned*)(outhi + (size_t)node * 64 + hl * 2) = (unsigned)h0 | ((unsigned)h1 << 16);
        *(unsigned*)(outlo + (size_t)node * 64 + hl * 2) = (unsigned)l0 | ((unsigned)l1 << 16);
      } else {
        *(float2*)(outf + (size_t)node * 64 + hl * 2) = make_float2(a0, a1);
      }
    }
  }

  if (RELU_STATS) {
    __shared__ float red[4][64];
    if (half == 0) {
      red[widx][hl * 2 + 0] = ls0;
      red[widx][hl * 2 + 1] = ls1;
    }
    __syncthreads();
    if (tid < 64) {
      atomicAdd(&stat[tid], red[0][tid] + red[1][tid] + red[2][tid] + red[3][tid]);
    }
    __syncthreads();
    if (half == 0) {
      red[widx][hl * 2 + 0] = lq0;
      red[widx][hl * 2 + 1] = lq1;
    }
    __syncthreads();
    if (tid < 64) {
      atomicAdd(&stat[256 + tid], red[0][tid] + red[1][tid] + red[2][tid] + red[3][tid]);
    }
  }
}

// ---------------- BN apply with inline finalize ----------------
template <int F, bool RELU, bool WF32, bool WB16, bool WSPLIT>
__global__ __launch_bounds__(256) void bn_apply_f(const float* __restrict__ a,
                                                  const float* __restrict__ stat,
                                                  const float* __restrict__ g,
                                                  const float* __restrict__ bb,
                                                  float* __restrict__ outf,
                                                  unsigned short* __restrict__ outb,
                                                  unsigned short* __restrict__ outhi,
                                                  unsigned short* __restrict__ outlo) {
  __shared__ float s_scale[F], s_shift[F];
  const int tid = threadIdx.x;
  if (tid < F) {
    const float invN = 1.0f / (float)N_NODES;
    float mean = stat[tid] * invN;
    float var = fmaxf(stat[256 + tid] * invN - mean * mean, 0.f);
    float inv = rsqrtf(var + BN_EPS);
    float sc = g[tid] * inv;
    s_scale[tid] = sc;
    s_shift[tid] = bb[tid] - mean * sc;
  }
  __syncthreads();
  constexpr int C4 = F / 4;
  const int total = N_NODES * C4;
  for (int idx = blockIdx.x * blockDim.x + tid; idx < total; idx += gridDim.x * blockDim.x) {
    int c4 = idx % C4;
    float4 v = ((const float4*)a)[idx];
    float4 s = *(float4*)&s_scale[c4 * 4];
    float4 sh = *(float4*)&s_shift[c4 * 4];
    float4 o;
    o.x = fmaf(v.x, s.x, sh.x);
    o.y = fmaf(v.y, s.y, sh.y);
    o.z = fmaf(v.z, s.z, sh.z);
    o.w = fmaf(v.w, s.w, sh.w);
    if (RELU) {
      o.x = fmaxf(o.x, 0.f);
      o.y = fmaxf(o.y, 0.f);
      o.z = fmaxf(o.z, 0.f);
      o.w = fmaxf(o.w, 0.f);
    }
    if (WF32) ((float4*)outf)[idx] = o;
    if (WB16) {
      ushort4 b;
      b.x = f2bf(o.x); b.y = f2bf(o.y); b.z = f2bf(o.z); b.w = f2bf(o.w);
      ((ushort4*)outb)[idx] = b;
    }
    if (WSPLIT) {
      ushort4 h, l;
      split2(o.x, h.x, l.x);
      split2(o.y, h.y, l.y);
      split2(o.z, h.z, l.z);
      split2(o.w, h.w, l.w);
      ((ushort4*)outhi)[idx] = h;
      ((ushort4*)outlo)[idx] = l;
    }
  }
}

extern "C" void kernel_launch(void* const* d_in, const int* in_sizes, int n_in,
                              void* d_out, int out_size, void* d_ws, size_t ws_size,
                              hipStream_t stream) {
  const float* x = (const float*)d_in[0];
  const int* ei = (const int*)d_in[1];
  const int E = in_sizes[1] / 2;
  const int* src = ei;
  const int* dst = ei + E;
  const float* We1 = (const float*)d_in[2];  const float* be1 = (const float*)d_in[3];
  const float* g1  = (const float*)d_in[4];  const float* bb1 = (const float*)d_in[5];
  const float* We2 = (const float*)d_in[6];  const float* be2 = (const float*)d_in[7];
  const float* g2  = (const float*)d_in[8];  const float* bb2 = (const float*)d_in[9];
  const float* Wd1 = (const float*)d_in[10]; const float* bd1 = (const float*)d_in[11];
  const float* g3  = (const float*)d_in[12]; const float* bb3 = (const float*)d_in[13];
  const float* Wd2 = (const float*)d_in[14]; const float* bd2 = (const float*)d_in[15];
  const float* g4  = (const float*)d_in[16]; const float* bb4 = (const float*)d_in[17];

  float* out = (float*)d_out;
  char* ws = (char*)d_ws;
  // Region A [0, 48MB): disjoint lifetimes per step:
  unsigned short* A0b  = (unsigned short*)(ws + 0);         // L1 gemm out 128ch bf16
  unsigned short* A1b  = (unsigned short*)(ws + 12800000);  // L2 gemm out 64ch bf16
  unsigned short* C2b  = (unsigned short*)(ws + 32000000);  // enc2 bf16 (L3 agg input)
  unsigned short* G3hi = (unsigned short*)(ws + 0);         // L3 agg out hi (6.4M)
  unsigned short* G3lo = (unsigned short*)(ws + 6400000);   // L3 agg out lo (6.4M)
  unsigned short* D3b  = (unsigned short*)(ws + 12800000);  // h3 bf16 (L4 agg input, 12.8M)
  unsigned short* G4hi = (unsigned short*)(ws + 0);         // L4 agg out hi (12.8M)
  unsigned short* G4lo = (unsigned short*)(ws + 25600000);  // L4 agg out lo (12.8M)
  unsigned short* Wb   = (unsigned short*)(ws + 48000000);  // weights, persist
  unsigned short* W1h = Wb;            unsigned short* W1l = W1h + 32768;
  unsigned short* W2h = W1l + 32768;   unsigned short* W2l = W2h + 8192;
  unsigned short* W3h = W2l + 8192;    unsigned short* W3l = W3h + 8192;
  unsigned short* W4h = W3l + 8192;    unsigned short* W4l = W4h + 32768;
  float* B0f  = (float*)(ws + 51200000);  // pre-BN fp32 (up to 51.2M at L4)
  int*   eslot  = (int*)(ws + 51200000);     // 3.2M; dead before first B0f write (agg L1)
  unsigned* csrU = (unsigned*)(ws + 102400000);  // packed CSR 4B x E (3.2M)
  float* stat4  = (float*)(ws + 108800000);  // 4 x 512 floats
  int*   bsum   = (int*)(ws + 108808192);    // 64 ints for hierarchical scan
  int*   counts = (int*)(ws + 108810000);    // reused as rowsum after scan_blocks
  int*   offs   = (int*)(ws + 109210000);
  float* dinv   = (float*)(ws + 109410064);
  if (ws_size < 109604160) return;
  float* rowsum = (float*)counts;  // counts dead after scan_blocks

  float* enc1 = out + (size_t)N_NODES * F0;
  float* enc2 = enc1 + (size_t)N_NODES * F1;

  const int EB = (E + 255) / 256;
  const int AGG_GRID = 2048;
  const int MB = (N_NODES + 127) / 128;        // 391
  const int SCAN_B = (N_NODES + 1023) / 1024;  // 49

  // conversions + CSR build
  convert_weights<<<320, 256, 0, stream>>>(We1, We2, Wd1, Wd2, W1h, W1l, W2h, W2l,
                                           W3h, W3l, W4h, W4l);
  hipMemsetAsync(counts, 0, N_NODES * sizeof(int), stream);
  hipMemsetAsync(stat4, 0, 4 * 512 * sizeof(float), stream);
  count_dst<<<EB, 256, 0, stream>>>(dst, counts, eslot, E);
  scan_blocks<<<SCAN_B, 256, 0, stream>>>(counts, offs, bsum, dinv);
  scan_tops<<<1, 64, 0, stream>>>(bsum, offs, SCAN_B);
  scan_add<<<SCAN_B, 256, 0, stream>>>(offs, bsum);
  fill_csr<<<EB, 256, 0, stream>>>(src, dst, offs, eslot, dinv, csrU, E);
  compute_rowsum<<<(N_NODES + 255) / 256, 256, 0, stream>>>(offs, csrU, dinv, rowsum);

  // ---- Layer 1: F0 -> F1 (propagate after) ----
  mfma_gemm_split<128, false, true><<<dim3(MB, 1), 512, 0, stream>>>(
      nullptr, nullptr, x, W1h, W1l, be1, nullptr, A0b, nullptr, nullptr, N_NODES, F0, F1);
  agg128_rl<true, false><<<AGG_GRID, 256, 0, stream>>>(
      A0b, offs, csrU, dinv, B0f, nullptr, nullptr, stat4);
  bn_apply_f<F1, true, true, false, false><<<2048, 256, 0, stream>>>(
      B0f, stat4, g1, bb1, enc1, nullptr, nullptr, nullptr);

  // ---- Layer 2: F1 -> F2 (propagate after); GEMM reads enc1 fp32, splits in staging ----
  mfma_gemm_split<64, false, true><<<dim3(MB, 1), 512, 0, stream>>>(
      nullptr, nullptr, enc1, W2h, W2l, be2, nullptr, A1b, nullptr, nullptr, N_NODES, F1, F2);
  agg64_rl<true, false><<<AGG_GRID, 256, 0, stream>>>(
      A1b, offs, csrU, dinv, B0f, nullptr, nullptr, stat4 + 512);
  bn_apply_f<F2, false, true, true, false><<<2048, 256, 0, stream>>>(
      B0f, stat4 + 512, g2, bb2, enc2, C2b, nullptr, nullptr);

  // ---- Layer 3: F2 -> F1 (propagate FIRST) ----
  agg64_rl<false, true><<<AGG_GRID, 256, 0, stream>>>(
      C2b, offs, csrU, dinv, nullptr, G3hi, G3lo, nullptr);
  mfma_gemm_split<128, true, false><<<dim3(MB, 1), 512, 0, stream>>>(
      G3hi, G3lo, nullptr, W3h, W3l, bd1, rowsum, nullptr, B0f, stat4 + 1024, N_NODES, F2, F1);
  bn_apply_f<F1, true, false, true, false><<<2048, 256, 0, stream>>>(
      B0f, stat4 + 1024, g3, bb3, nullptr, D3b, nullptr, nullptr);

  // ---- Layer 4: F1 -> F0 (propagate FIRST) ----
  agg128_rl<false, true><<<AGG_GRID, 256, 0, stream>>>(
      D3b, offs, csrU, dinv, nullptr, G4hi, G4lo, nullptr);
  mfma_gemm_split<128, true, false><<<dim3(MB, 2), 512, 0, stream>>>(
      G4hi, G4lo, nullptr, W4h, W4l, bd2, rowsum, nullptr, B0f, stat4 + 1536, N_NODES, F1, F0);
  bn_apply_f<F0, false, true, false, false><<<2048, 256, 0, stream>>>(
      B0f, stat4 + 1536, g4, bb4, out, nullptr, nullptr, nullptr);
}

// Round 10
// 566.068 us; speedup vs baseline: 1.2660x; 1.0942x over previous
//
#include <hip/hip_runtime.h>
#include <hip/hip_fp16.h>

#define N_NODES 50000
#define F0 256
#define F1 128
#define F2 64
#define BN_EPS 1e-5f

typedef float f32x4 __attribute__((ext_vector_type(4)));
typedef __bf16 bf16x8 __attribute__((ext_vector_type(8)));
typedef unsigned short ushort8v __attribute__((ext_vector_type(8)));

__device__ __forceinline__ float bflo(unsigned v) { return __uint_as_float(v << 16); }
__device__ __forceinline__ float bfhi(unsigned v) { return __uint_as_float(v & 0xFFFF0000u); }
__device__ __forceinline__ unsigned short f2bf(float f) {
  unsigned u = __float_as_uint(f);
  u += 0x7FFFu + ((u >> 16) & 1u);
  return (unsigned short)(u >> 16);
}
__device__ __forceinline__ void split2(float a, unsigned short& hi, unsigned short& lo) {
  hi = f2bf(a);
  float hf = __uint_as_float((unsigned)hi << 16);
  lo = f2bf(a - hf);
}
__device__ __forceinline__ int rdl(int v, int l) { return __builtin_amdgcn_readlane(v, l); }
__device__ __forceinline__ float h2f(unsigned short h) {
  __half hh = *reinterpret_cast<__half*>(&h);
  return __half2float(hh);
}
__device__ __forceinline__ unsigned short f2h(float f) {
  __half hh = __float2half(f);
  return *reinterpret_cast<unsigned short*>(&hh);
}

// ---------------- CSR build ----------------
__global__ void count_dst(const int* __restrict__ dst, int* __restrict__ counts,
                          int* __restrict__ eslot, int E) {
  int e = blockIdx.x * blockDim.x + threadIdx.x;
  if (e < E) eslot[e] = atomicAdd(&counts[dst[e]], 1);
}

__global__ __launch_bounds__(256) void scan_blocks(const int* __restrict__ counts,
                                                   int* __restrict__ offs,
                                                   int* __restrict__ bsum,
                                                   float* __restrict__ dinv) {
  __shared__ int s_w[4];
  const int tid = threadIdx.x, lane = tid & 63, wid = tid >> 6;
  const int base = blockIdx.x * 1024 + tid * 4;
  int v0 = 0, v1 = 0, v2 = 0, v3 = 0;
  if (base + 3 < N_NODES) {
    int4 v = *(const int4*)(counts + base);
    v0 = v.x; v1 = v.y; v2 = v.z; v3 = v.w;
  } else if (base < N_NODES) {
    v0 = counts[base];
    if (base + 1 < N_NODES) v1 = counts[base + 1];
    if (base + 2 < N_NODES) v2 = counts[base + 2];
  }
  if (base < N_NODES) {
    dinv[base] = rsqrtf((float)v0 + 1.0f);
    if (base + 1 < N_NODES) dinv[base + 1] = rsqrtf((float)v1 + 1.0f);
    if (base + 2 < N_NODES) dinv[base + 2] = rsqrtf((float)v2 + 1.0f);
    if (base + 3 < N_NODES) dinv[base + 3] = rsqrtf((float)v3 + 1.0f);
  }
  int t = v0 + v1 + v2 + v3;
  int incl = t;
#pragma unroll
  for (int d = 1; d < 64; d <<= 1) {
    int x = __shfl_up(incl, d);
    if (lane >= d) incl += x;
  }
  if (lane == 63) s_w[wid] = incl;
  __syncthreads();
  int woff = 0;
#pragma unroll
  for (int j = 0; j < 4; j++)
    if (j < wid) woff += s_w[j];
  int p = woff + incl - t;
  if (base < N_NODES) offs[base] = p;
  p += v0;
  if (base + 1 < N_NODES) offs[base + 1] = p;
  p += v1;
  if (base + 2 < N_NODES) offs[base + 2] = p;
  p += v2;
  if (base + 3 < N_NODES) offs[base + 3] = p;
  if (tid == 255) bsum[blockIdx.x] = woff + incl;
}

__global__ void scan_tops(int* __restrict__ bsum, int* __restrict__ offs, int nblk) {
  int lane = threadIdx.x;
  int v = (lane < nblk) ? bsum[lane] : 0;
  int incl = v;
#pragma unroll
  for (int d = 1; d < 64; d <<= 1) {
    int x = __shfl_up(incl, d);
    if (lane >= d) incl += x;
  }
  if (lane < nblk) bsum[lane] = incl - v;
  if (lane == 63) offs[N_NODES] = incl;
}

__global__ __launch_bounds__(256) void scan_add(int* __restrict__ offs,
                                                const int* __restrict__ bsum) {
  const int add = bsum[blockIdx.x];
  const int base = blockIdx.x * 1024 + threadIdx.x * 4;
  if (base + 3 < N_NODES) {
    int4 v = *(const int4*)(offs + base);
    v.x += add; v.y += add; v.z += add; v.w += add;
    *(int4*)(offs + base) = v;
  } else if (base < N_NODES) {
    offs[base] += add;
    if (base + 1 < N_NODES) offs[base + 1] += add;
    if (base + 2 < N_NODES) offs[base + 2] += add;
  }
}

// pure gather->scatter: 4B packed entry {src:16, fp16(dinv[src]):16}
__global__ void fill_csr(const int* __restrict__ src, const int* __restrict__ dst,
                         const int* __restrict__ offs, const int* __restrict__ eslot,
                         const float* __restrict__ dinv,
                         unsigned* __restrict__ csrU, int E) {
  int e = blockIdx.x * blockDim.x + threadIdx.x;
  if (e < E) {
    int s = src[e], d = dst[e];
    int p = offs[d] + eslot[e];
    unsigned ent = (unsigned)s | ((unsigned)f2h(dinv[s]) << 16);
    __builtin_nontemporal_store(ent, &csrU[p]);
  }
}

__global__ void compute_rowsum(const int* __restrict__ offs,
                               const unsigned* __restrict__ csrU,
                               const float* __restrict__ dinv, float* __restrict__ rowsum) {
  int i = blockIdx.x * blockDim.x + threadIdx.x;
  if (i < N_NODES) {
    float di = dinv[i];
    float s = di;
    int e1 = offs[i + 1];
    for (int e = offs[i]; e < e1; e++) s += h2f((unsigned short)(csrU[e] >> 16));
    rowsum[i] = di * s;
  }
}

// ---------------- merged weight conversion: W[K][N] fp32 -> hi/lo [N][K] bf16 ----------------
__device__ __forceinline__ void wt_one(const float* W, unsigned short* Wh, unsigned short* Wl,
                                       int K, int N, int idx) {
  int k = idx / N, n = idx - k * N;
  unsigned short h, l;
  split2(W[idx], h, l);
  Wh[(size_t)n * K + k] = h;
  Wl[(size_t)n * K + k] = l;
}

__global__ void convert_weights(const float* __restrict__ We1, const float* __restrict__ We2,
                                const float* __restrict__ Wd1, const float* __restrict__ Wd2,
                                unsigned short* W1h, unsigned short* W1l,
                                unsigned short* W2h, unsigned short* W2l,
                                unsigned short* W3h, unsigned short* W3l,
                                unsigned short* W4h, unsigned short* W4l) {
  int idx = blockIdx.x * blockDim.x + threadIdx.x;
  if (idx < 32768) {
    wt_one(We1, W1h, W1l, 256, 128, idx);
  } else if (idx < 40960) {
    wt_one(We2, W2h, W2l, 128, 64, idx - 32768);
  } else if (idx < 49152) {
    wt_one(Wd1, W3h, W3l, 64, 128, idx - 40960);
  } else if (idx < 81920) {
    wt_one(Wd2, W4h, W4l, 128, 256, idx - 49152);
  }
}

// ---------------- split-bf16 MFMA GEMM (R7 256-thread shape) ----------------
// STATS=true: no global atomics -- per-block partials to spart[bx][2N] (LDS-reduced).
template <int BN, bool STATS, bool AF32>
__global__ __launch_bounds__(256) void mfma_gemm_split(
    const unsigned short* __restrict__ Ahi, const unsigned short* __restrict__ Alo,
    const float* __restrict__ Af,
    const unsigned short* __restrict__ Whi, const unsigned short* __restrict__ Wlo,
    const float* __restrict__ bias, const float* __restrict__ rowsum,
    unsigned short* __restrict__ Cb, float* __restrict__ Cf,
    float* __restrict__ spart, int M, int K, int N) {
  constexpr int BM = 128;
  constexpr int MT = (BN == 128) ? 4 : 2;
  constexpr int NT = 4;
  __shared__ __align__(16) unsigned short AsH[4][BM][8];
  __shared__ __align__(16) unsigned short AsL[4][BM][8];
  __shared__ __align__(16) unsigned short BsH[4][BN][8];
  __shared__ __align__(16) unsigned short BsL[4][BN][8];
  __shared__ float sls[BN], slq[BN];
  const int tid = threadIdx.x;
  const int lane = tid & 63, wid = tid >> 6;
  const int quad = lane >> 4, ln = lane & 15;
  const int m0 = blockIdx.x * BM;
  const int n0 = blockIdx.y * BN;
  const int wm = (BN == 128) ? (wid & 1) * 64 : wid * 32;
  const int wn = (BN == 128) ? (wid >> 1) * 64 : 0;
  f32x4 acc[MT][NT] = {};
  if (STATS && tid < BN) {
    sls[tid] = 0.f;
    slq[tid] = 0.f;
  }

  const int arow = tid >> 2, aseg = tid & 3;
  for (int k0 = 0; k0 < K; k0 += 32) {
#pragma unroll
    for (int i = 0; i < 2; i++) {
      int row = arow + i * 64;
      int gm = m0 + row;
      if (AF32) {
        float4 u0 = make_float4(0.f, 0.f, 0.f, 0.f), u1 = u0;
        if (gm < M) {
          u0 = *(const float4*)(Af + (size_t)gm * K + k0 + aseg * 8);
          u1 = *(const float4*)(Af + (size_t)gm * K + k0 + aseg * 8 + 4);
        }
        ushort4 h0, l0, h1, l1;
        split2(u0.x, h0.x, l0.x); split2(u0.y, h0.y, l0.y);
        split2(u0.z, h0.z, l0.z); split2(u0.w, h0.w, l0.w);
        split2(u1.x, h1.x, l1.x); split2(u1.y, h1.y, l1.y);
        split2(u1.z, h1.z, l1.z); split2(u1.w, h1.w, l1.w);
        *(ushort4*)(&AsH[aseg][row][0]) = h0;
        *(ushort4*)(&AsH[aseg][row][4]) = h1;
        *(ushort4*)(&AsL[aseg][row][0]) = l0;
        *(ushort4*)(&AsL[aseg][row][4]) = l1;
      } else {
        ushort8v vh = {0, 0, 0, 0, 0, 0, 0, 0};
        ushort8v vl = {0, 0, 0, 0, 0, 0, 0, 0};
        if (gm < M) {
          vh = *(const ushort8v*)(Ahi + (size_t)gm * K + k0 + aseg * 8);
          vl = *(const ushort8v*)(Alo + (size_t)gm * K + k0 + aseg * 8);
        }
        *(ushort8v*)(&AsH[aseg][row][0]) = vh;
        *(ushort8v*)(&AsL[aseg][row][0]) = vl;
      }
    }
#pragma unroll
    for (int i = 0; i < BN / 64; i++) {
      int n = arow + i * 64;
      *(ushort8v*)(&BsH[aseg][n][0]) =
          *(const ushort8v*)(Whi + (size_t)(n0 + n) * K + k0 + aseg * 8);
      *(ushort8v*)(&BsL[aseg][n][0]) =
          *(const ushort8v*)(Wlo + (size_t)(n0 + n) * K + k0 + aseg * 8);
    }
    __syncthreads();
    bf16x8 ah[MT], al[MT], bh[NT], bl[NT];
#pragma unroll
    for (int mt = 0; mt < MT; mt++) {
      ah[mt] = *(const bf16x8*)(&AsH[quad][wm + mt * 16 + ln][0]);
      al[mt] = *(const bf16x8*)(&AsL[quad][wm + mt * 16 + ln][0]);
    }
#pragma unroll
    for (int nt = 0; nt < NT; nt++) {
      bh[nt] = *(const bf16x8*)(&BsH[quad][wn + nt * 16 + ln][0]);
      bl[nt] = *(const bf16x8*)(&BsL[quad][wn + nt * 16 + ln][0]);
    }
#pragma unroll
    for (int mt = 0; mt < MT; mt++)
#pragma unroll
      for (int nt = 0; nt < NT; nt++) {
        acc[mt][nt] = __builtin_amdgcn_mfma_f32_16x16x32_bf16(ah[mt], bl[nt], acc[mt][nt], 0, 0, 0);
        acc[mt][nt] = __builtin_amdgcn_mfma_f32_16x16x32_bf16(al[mt], bh[nt], acc[mt][nt], 0, 0, 0);
        acc[mt][nt] = __builtin_amdgcn_mfma_f32_16x16x32_bf16(ah[mt], bh[nt], acc[mt][nt], 0, 0, 0);
      }
    __syncthreads();
  }

  if (!STATS) {
#pragma unroll
    for (int nt = 0; nt < NT; nt++) {
      int gn = n0 + wn + nt * 16 + ln;
      float bv = bias[gn];
#pragma unroll
      for (int mt = 0; mt < MT; mt++) {
#pragma unroll
        for (int r = 0; r < 4; r++) {
          int gm = m0 + wm + mt * 16 + quad * 4 + r;
          if (gm < M) Cb[(size_t)gm * N + gn] = f2bf(acc[mt][nt][r] + bv);
        }
      }
    }
  } else {
    float rs[MT][4];
#pragma unroll
    for (int mt = 0; mt < MT; mt++)
#pragma unroll
      for (int r = 0; r < 4; r++) {
        int gm = m0 + wm + mt * 16 + quad * 4 + r;
        rs[mt][r] = (gm < M) ? rowsum[gm] : 0.f;
      }
#pragma unroll
    for (int nt = 0; nt < NT; nt++) {
      int gn = n0 + wn + nt * 16 + ln;
      float bv = bias[gn];
      float ls = 0.f, lq = 0.f;
#pragma unroll
      for (int mt = 0; mt < MT; mt++) {
#pragma unroll
        for (int r = 0; r < 4; r++) {
          int gm = m0 + wm + mt * 16 + quad * 4 + r;
          if (gm < M) {
            float v = fmaxf(fmaf(bv, rs[mt][r], acc[mt][nt][r]), 0.f);
            Cf[(size_t)gm * N + gn] = v;
            ls += v;
            lq = fmaf(v, v, lq);
          }
        }
      }
      ls += __shfl_xor(ls, 16); ls += __shfl_xor(ls, 32);
      lq += __shfl_xor(lq, 16); lq += __shfl_xor(lq, 32);
      if (quad == 0) {
        atomicAdd(&sls[wn + nt * 16 + ln], ls);
        atomicAdd(&slq[wn + nt * 16 + ln], lq);
      }
    }
    __syncthreads();
    if (tid < BN) {
      size_t base = (size_t)blockIdx.x * (2 * N);
      spart[base + n0 + tid] = sls[tid];
      spart[base + N + n0 + tid] = slq[tid];
    }
  }
}

// reduce per-block GEMM stat partials: stat[c] = sum_bx spart[bx][c]
__global__ __launch_bounds__(256) void reduce_stats(const float* __restrict__ spart,
                                                    float* __restrict__ stat, int nbx, int N) {
  const int c = blockIdx.x;  // column 0..N-1
  const int t = threadIdx.x;
  const int N2 = 2 * N;
  float ls = 0.f, lq = 0.f;
  for (int b = t; b < nbx; b += 256) {
    ls += spart[(size_t)b * N2 + c];
    lq += spart[(size_t)b * N2 + N + c];
  }
#pragma unroll
  for (int d = 1; d < 64; d <<= 1) {
    ls += __shfl_xor(ls, d);
    lq += __shfl_xor(lq, d);
  }
  __shared__ float rl[4], rq[4];
  if ((t & 63) == 0) {
    rl[t >> 6] = ls;
    rq[t >> 6] = lq;
  }
  __syncthreads();
  if (t == 0) {
    stat[c] = rl[0] + rl[1] + rl[2] + rl[3];
    stat[256 + c] = rq[0] + rq[1] + rq[2] + rq[3];
  }
}

// ---------------- agg F=128, packed-u32 readlane broadcast, one node per wave ----------------
template <bool RELU_STATS, bool OUT_SPLIT>
__global__ __launch_bounds__(256) void agg128_rl(
    const unsigned short* __restrict__ hb, const int* __restrict__ offs,
    const unsigned* __restrict__ csrU, const float* __restrict__ dinv,
    float* __restrict__ outf, unsigned short* __restrict__ outhi,
    unsigned short* __restrict__ outlo, float* __restrict__ stat) {
  const int tid = threadIdx.x;
  const int lane = tid & 63;
  const int widx = tid >> 6;
  const int nwaves = gridDim.x * 4;
  float ls0 = 0.f, ls1 = 0.f, lq0 = 0.f, lq1 = 0.f;

  for (int node = blockIdx.x * 4 + widx; node < N_NODES; node += nwaves) {
    const int e0 = __builtin_amdgcn_readfirstlane(offs[node]);
    const int e1 = __builtin_amdgcn_readfirstlane(offs[node + 1]);
    float a0 = 0.f, a1 = 0.f;
    for (int e = e0; e < e1; e += 64) {
      const int cnt = min(64, e1 - e);
      unsigned ent = 0;
      if (lane < cnt) ent = csrU[e + lane];
      const int nb = (cnt + 7) & ~7;
      for (int j = 0; j < nb; j += 8) {
#pragma unroll
        for (int u = 0; u < 8; u++) {
          unsigned ce = (unsigned)rdl((int)ent, j + u);
          int s = (int)(ce & 0xFFFFu);
          float w = h2f((unsigned short)(ce >> 16));
          unsigned v = *(const unsigned*)(hb + (size_t)s * 128 + lane * 2);
          a0 = fmaf(bflo(v), w, a0);
          a1 = fmaf(bfhi(v), w, a1);
        }
      }
    }
    float di = dinv[node];
    unsigned vs = *(const unsigned*)(hb + (size_t)node * 128 + lane * 2);
    a0 = fmaf(bflo(vs), di, a0) * di;
    a1 = fmaf(bfhi(vs), di, a1) * di;
    if (RELU_STATS) {
      a0 = fmaxf(a0, 0.f);
      a1 = fmaxf(a1, 0.f);
      ls0 += a0; ls1 += a1;
      lq0 = fmaf(a0, a0, lq0);
      lq1 = fmaf(a1, a1, lq1);
    }
    if (OUT_SPLIT) {
      unsigned short h0, l0, h1, l1;
      split2(a0, h0, l0);
      split2(a1, h1, l1);
      *(unsigned*)(outhi + (size_t)node * 128 + lane * 2) = (unsigned)h0 | ((unsigned)h1 << 16);
      *(unsigned*)(outlo + (size_t)node * 128 + lane * 2) = (unsigned)l0 | ((unsigned)l1 << 16);
    } else {
      *(float2*)(outf + (size_t)node * 128 + lane * 2) = make_float2(a0, a1);
    }
  }

  if (RELU_STATS) {
    __shared__ float red[4][128];
    red[widx][lane * 2 + 0] = ls0;
    red[widx][lane * 2 + 1] = ls1;
    __syncthreads();
    if (tid < 128) {
      atomicAdd(&stat[tid], red[0][tid] + red[1][tid] + red[2][tid] + red[3][tid]);
    }
    __syncthreads();
    red[widx][lane * 2 + 0] = lq0;
    red[widx][lane * 2 + 1] = lq1;
    __syncthreads();
    if (tid < 128) {
      atomicAdd(&stat[256 + tid], red[0][tid] + red[1][tid] + red[2][tid] + red[3][tid]);
    }
  }
}

// ---------------- agg F=64, packed-u32 readlane broadcast, two edges per gather ----------------
template <bool RELU_STATS, bool OUT_SPLIT>
__global__ __launch_bounds__(256) void agg64_rl(
    const unsigned short* __restrict__ hb, const int* __restrict__ offs,
    const unsigned* __restrict__ csrU, const float* __restrict__ dinv,
    float* __restrict__ outf, unsigned short* __restrict__ outhi,
    unsigned short* __restrict__ outlo, float* __restrict__ stat) {
  const int tid = threadIdx.x;
  const int lane = tid & 63;
  const int widx = tid >> 6;
  const int half = lane >> 5;
  const int hl = lane & 31;
  const int nwaves = gridDim.x * 4;
  float ls0 = 0.f, ls1 = 0.f, lq0 = 0.f, lq1 = 0.f;

  for (int node = blockIdx.x * 4 + widx; node < N_NODES; node += nwaves) {
    const int e0 = __builtin_amdgcn_readfirstlane(offs[node]);
    const int e1 = __builtin_amdgcn_readfirstlane(offs[node + 1]);
    float a0 = 0.f, a1 = 0.f;
    for (int e = e0; e < e1; e += 64) {
      const int cnt = min(64, e1 - e);
      unsigned ent = 0;
      if (lane < cnt) ent = csrU[e + lane];
      const int nb = (cnt + 15) & ~15;
      for (int j = 0; j < nb; j += 16) {
#pragma unroll
        for (int u = 0; u < 8; u++) {
          unsigned ca = (unsigned)rdl((int)ent, j + 2 * u);
          unsigned cb = (unsigned)rdl((int)ent, j + 2 * u + 1);
          unsigned ce = half ? cb : ca;
          int s = (int)(ce & 0xFFFFu);
          float w = h2f((unsigned short)(ce >> 16));
          unsigned v = *(const unsigned*)(hb + (size_t)s * 64 + hl * 2);
          a0 = fmaf(bflo(v), w, a0);
          a1 = fmaf(bfhi(v), w, a1);
        }
      }
    }
    a0 += __shfl_xor(a0, 32);
    a1 += __shfl_xor(a1, 32);
    float di = dinv[node];
    unsigned vs = *(const unsigned*)(hb + (size_t)node * 64 + hl * 2);
    a0 = fmaf(bflo(vs), di, a0) * di;
    a1 = fmaf(bfhi(vs), di, a1) * di;
    if (RELU_STATS) {
      a0 = fmaxf(a0, 0.f);
      a1 = fmaxf(a1, 0.f);
      if (half == 0) {
        ls0 += a0; ls1 += a1;
        lq0 = fmaf(a0, a0, lq0);
        lq1 = fmaf(a1, a1, lq1);
      }
    }
    if (half == 0) {
      if (OUT_SPLIT) {
        unsigned short h0, l0, h1, l1;
        split2(a0, h0, l0);
        split2(a1, h1, l1);
        *(unsigned*)(outhi + (size_t)node * 64 + hl * 2) = (unsigned)h0 | ((unsigned)h1 << 16);
        *(unsigned*)(outlo + (size_t)node * 64 + hl * 2) = (unsigned)l0 | ((unsigned)l1 << 16);
      } else {
        *(float2*)(outf + (size_t)node * 64 + hl * 2) = make_float2(a0, a1);
      }
    }
  }

  if (RELU_STATS) {
    __shared__ float red[4][64];
    if (half == 0) {
      red[widx][hl * 2 + 0] = ls0;
      red[widx][hl * 2 + 1] = ls1;
    }
    __syncthreads();
    if (tid < 64) {
      atomicAdd(&stat[tid], red[0][tid] + red[1][tid] + red[2][tid] + red[3][tid]);
    }
    __syncthreads();
    if (half == 0) {
      red[widx][hl * 2 + 0] = lq0;
      red[widx][hl * 2 + 1] = lq1;
    }
    __syncthreads();
    if (tid < 64) {
      atomicAdd(&stat[256 + tid], red[0][tid] + red[1][tid] + red[2][tid] + red[3][tid]);
    }
  }
}

// ---------------- BN apply with inline finalize ----------------
template <int F, bool RELU, bool WF32, bool WB16, bool WSPLIT>
__global__ __launch_bounds__(256) void bn_apply_f(const float* __restrict__ a,
                                                  const float* __restrict__ stat,
                                                  const float* __restrict__ g,
                                                  const float* __restrict__ bb,
                                                  float* __restrict__ outf,
                                                  unsigned short* __restrict__ outb,
                                                  unsigned short* __restrict__ outhi,
                                                  unsigned short* __restrict__ outlo) {
  __shared__ float s_scale[F], s_shift[F];
  const int tid = threadIdx.x;
  if (tid < F) {
    const float invN = 1.0f / (float)N_NODES;
    float mean = stat[tid] * invN;
    float var = fmaxf(stat[256 + tid] * invN - mean * mean, 0.f);
    float inv = rsqrtf(var + BN_EPS);
    float sc = g[tid] * inv;
    s_scale[tid] = sc;
    s_shift[tid] = bb[tid] - mean * sc;
  }
  __syncthreads();
  constexpr int C4 = F / 4;
  const int total = N_NODES * C4;
  for (int idx = blockIdx.x * blockDim.x + tid; idx < total; idx += gridDim.x * blockDim.x) {
    int c4 = idx % C4;
    float4 v = ((const float4*)a)[idx];
    float4 s = *(float4*)&s_scale[c4 * 4];
    float4 sh = *(float4*)&s_shift[c4 * 4];
    float4 o;
    o.x = fmaf(v.x, s.x, sh.x);
    o.y = fmaf(v.y, s.y, sh.y);
    o.z = fmaf(v.z, s.z, sh.z);
    o.w = fmaf(v.w, s.w, sh.w);
    if (RELU) {
      o.x = fmaxf(o.x, 0.f);
      o.y = fmaxf(o.y, 0.f);
      o.z = fmaxf(o.z, 0.f);
      o.w = fmaxf(o.w, 0.f);
    }
    if (WF32) ((float4*)outf)[idx] = o;
    if (WB16) {
      ushort4 b;
      b.x = f2bf(o.x); b.y = f2bf(o.y); b.z = f2bf(o.z); b.w = f2bf(o.w);
      ((ushort4*)outb)[idx] = b;
    }
    if (WSPLIT) {
      ushort4 h, l;
      split2(o.x, h.x, l.x);
      split2(o.y, h.y, l.y);
      split2(o.z, h.z, l.z);
      split2(o.w, h.w, l.w);
      ((ushort4*)outhi)[idx] = h;
      ((ushort4*)outlo)[idx] = l;
    }
  }
}

extern "C" void kernel_launch(void* const* d_in, const int* in_sizes, int n_in,
                              void* d_out, int out_size, void* d_ws, size_t ws_size,
                              hipStream_t stream) {
  const float* x = (const float*)d_in[0];
  const int* ei = (const int*)d_in[1];
  const int E = in_sizes[1] / 2;
  const int* src = ei;
  const int* dst = ei + E;
  const float* We1 = (const float*)d_in[2];  const float* be1 = (const float*)d_in[3];
  const float* g1  = (const float*)d_in[4];  const float* bb1 = (const float*)d_in[5];
  const float* We2 = (const float*)d_in[6];  const float* be2 = (const float*)d_in[7];
  const float* g2  = (const float*)d_in[8];  const float* bb2 = (const float*)d_in[9];
  const float* Wd1 = (const float*)d_in[10]; const float* bd1 = (const float*)d_in[11];
  const float* g3  = (const float*)d_in[12]; const float* bb3 = (const float*)d_in[13];
  const float* Wd2 = (const float*)d_in[14]; const float* bd2 = (const float*)d_in[15];
  const float* g4  = (const float*)d_in[16]; const float* bb4 = (const float*)d_in[17];

  float* out = (float*)d_out;
  char* ws = (char*)d_ws;
  // Region A [0, 48MB): disjoint lifetimes per step:
  unsigned short* A0b  = (unsigned short*)(ws + 0);         // L1 gemm out 128ch bf16
  unsigned short* A1b  = (unsigned short*)(ws + 12800000);  // L2 gemm out 64ch bf16
  unsigned short* C2b  = (unsigned short*)(ws + 32000000);  // enc2 bf16 (L3 agg input)
  unsigned short* G3hi = (unsigned short*)(ws + 0);         // L3 agg out hi (6.4M)
  unsigned short* G3lo = (unsigned short*)(ws + 6400000);   // L3 agg out lo (6.4M)
  unsigned short* D3b  = (unsigned short*)(ws + 12800000);  // h3 bf16 (L4 agg input, 12.8M)
  unsigned short* G4hi = (unsigned short*)(ws + 0);         // L4 agg out hi (12.8M)
  unsigned short* G4lo = (unsigned short*)(ws + 25600000);  // L4 agg out lo (12.8M)
  unsigned short* Wb   = (unsigned short*)(ws + 48000000);  // weights, persist
  unsigned short* W1h = Wb;            unsigned short* W1l = W1h + 32768;
  unsigned short* W2h = W1l + 32768;   unsigned short* W2l = W2h + 8192;
  unsigned short* W3h = W2l + 8192;    unsigned short* W3l = W3h + 8192;
  unsigned short* W4h = W3l + 8192;    unsigned short* W4l = W4h + 32768;
  float* B0f  = (float*)(ws + 51200000);  // pre-BN fp32 (up to 51.2M at L4)
  int*   eslot  = (int*)(ws + 51200000);     // 3.2M; dead before first B0f write (agg L1)
  unsigned* csrU = (unsigned*)(ws + 102400000);  // packed CSR 4B x E (3.2M)
  float* spart  = (float*)(ws + 105600000);  // GEMM stat partials: 391 x 512 floats (800KB)
  float* stat4  = (float*)(ws + 108800000);  // 4 x 512 floats
  int*   bsum   = (int*)(ws + 108808192);    // 64 ints for hierarchical scan
  int*   counts = (int*)(ws + 108810000);    // reused as rowsum after scan_blocks
  int*   offs   = (int*)(ws + 109210000);
  float* dinv   = (float*)(ws + 109410064);
  if (ws_size < 109604160) return;
  float* rowsum = (float*)counts;  // counts dead after scan_blocks

  float* enc1 = out + (size_t)N_NODES * F0;
  float* enc2 = enc1 + (size_t)N_NODES * F1;

  const int EB = (E + 255) / 256;
  const int AGG_GRID = 2048;
  const int MB = (N_NODES + 127) / 128;        // 391
  const int SCAN_B = (N_NODES + 1023) / 1024;  // 49

  // conversions + CSR build
  convert_weights<<<320, 256, 0, stream>>>(We1, We2, Wd1, Wd2, W1h, W1l, W2h, W2l,
                                           W3h, W3l, W4h, W4l);
  hipMemsetAsync(counts, 0, N_NODES * sizeof(int), stream);
  hipMemsetAsync(stat4, 0, 4 * 512 * sizeof(float), stream);
  count_dst<<<EB, 256, 0, stream>>>(dst, counts, eslot, E);
  scan_blocks<<<SCAN_B, 256, 0, stream>>>(counts, offs, bsum, dinv);
  scan_tops<<<1, 64, 0, stream>>>(bsum, offs, SCAN_B);
  scan_add<<<SCAN_B, 256, 0, stream>>>(offs, bsum);
  fill_csr<<<EB, 256, 0, stream>>>(src, dst, offs, eslot, dinv, csrU, E);
  compute_rowsum<<<(N_NODES + 255) / 256, 256, 0, stream>>>(offs, csrU, dinv, rowsum);

  // ---- Layer 1: F0 -> F1 (propagate after) ----
  mfma_gemm_split<128, false, true><<<dim3(MB, 1), 256, 0, stream>>>(
      nullptr, nullptr, x, W1h, W1l, be1, nullptr, A0b, nullptr, nullptr, N_NODES, F0, F1);
  agg128_rl<true, false><<<AGG_GRID, 256, 0, stream>>>(
      A0b, offs, csrU, dinv, B0f, nullptr, nullptr, stat4);
  bn_apply_f<F1, true, true, false, false><<<2048, 256, 0, stream>>>(
      B0f, stat4, g1, bb1, enc1, nullptr, nullptr, nullptr);

  // ---- Layer 2: F1 -> F2 (propagate after); GEMM reads enc1 fp32, splits in staging ----
  mfma_gemm_split<64, false, true><<<dim3(MB, 1), 256, 0, stream>>>(
      nullptr, nullptr, enc1, W2h, W2l, be2, nullptr, A1b, nullptr, nullptr, N_NODES, F1, F2);
  agg64_rl<true, false><<<AGG_GRID, 256, 0, stream>>>(
      A1b, offs, csrU, dinv, B0f, nullptr, nullptr, stat4 + 512);
  bn_apply_f<F2, false, true, true, false><<<2048, 256, 0, stream>>>(
      B0f, stat4 + 512, g2, bb2, enc2, C2b, nullptr, nullptr);

  // ---- Layer 3: F2 -> F1 (propagate FIRST) ----
  agg64_rl<false, true><<<AGG_GRID, 256, 0, stream>>>(
      C2b, offs, csrU, dinv, nullptr, G3hi, G3lo, nullptr);
  mfma_gemm_split<128, true, false><<<dim3(MB, 1), 256, 0, stream>>>(
      G3hi, G3lo, nullptr, W3h, W3l, bd1, rowsum, nullptr, B0f, spart, N_NODES, F2, F1);
  reduce_stats<<<F1, 256, 0, stream>>>(spart, stat4 + 1024, MB, F1);
  bn_apply_f<F1, true, false, true, false><<<2048, 256, 0, stream>>>(
      B0f, stat4 + 1024, g3, bb3, nullptr, D3b, nullptr, nullptr);

  // ---- Layer 4: F1 -> F0 (propagate FIRST) ----
  agg128_rl<false, true><<<AGG_GRID, 256, 0, stream>>>(
      D3b, offs, csrU, dinv, nullptr, G4hi, G4lo, nullptr);
  mfma_gemm_split<128, true, false><<<dim3(MB, 2), 256, 0, stream>>>(
      G4hi, G4lo, nullptr, W4h, W4l, bd2, rowsum, nullptr, B0f, spart, N_NODES, F1, F0);
  reduce_stats<<<F0, 256, 0, stream>>>(spart, stat4 + 1536, MB, F0);
  bn_apply_f<F0, false, true, false, false><<<2048, 256, 0, stream>>>(
      B0f, stat4 + 1536, g4, bb4, out, nullptr, nullptr, nullptr);
}

// Round 11
// 545.420 us; speedup vs baseline: 1.3139x; 1.0379x over previous
//
#include <hip/hip_runtime.h>
#include <hip/hip_fp16.h>

#define N_NODES 50000
#define F0 256
#define F1 128
#define F2 64
#define BN_EPS 1e-5f

typedef float f32x4 __attribute__((ext_vector_type(4)));
typedef __bf16 bf16x8 __attribute__((ext_vector_type(8)));
typedef unsigned short ushort8v __attribute__((ext_vector_type(8)));

__device__ __forceinline__ float bflo(unsigned v) { return __uint_as_float(v << 16); }
__device__ __forceinline__ float bfhi(unsigned v) { return __uint_as_float(v & 0xFFFF0000u); }
__device__ __forceinline__ unsigned short f2bf(float f) {
  unsigned u = __float_as_uint(f);
  u += 0x7FFFu + ((u >> 16) & 1u);
  return (unsigned short)(u >> 16);
}
__device__ __forceinline__ void split2(float a, unsigned short& hi, unsigned short& lo) {
  hi = f2bf(a);
  float hf = __uint_as_float((unsigned)hi << 16);
  lo = f2bf(a - hf);
}
__device__ __forceinline__ int rdl(int v, int l) { return __builtin_amdgcn_readlane(v, l); }
__device__ __forceinline__ float h2f(unsigned short h) {
  __half hh = *reinterpret_cast<__half*>(&h);
  return __half2float(hh);
}
__device__ __forceinline__ unsigned short f2h(float f) {
  __half hh = __float2half(f);
  return *reinterpret_cast<unsigned short*>(&hh);
}

// ---------------- CSR build ----------------
__global__ void count_dst(const int* __restrict__ dst, int* __restrict__ counts,
                          int* __restrict__ eslot, int E) {
  int e = blockIdx.x * blockDim.x + threadIdx.x;
  if (e < E) eslot[e] = atomicAdd(&counts[dst[e]], 1);
}

__global__ __launch_bounds__(256) void scan_blocks(const int* __restrict__ counts,
                                                   int* __restrict__ offs,
                                                   int* __restrict__ bsum,
                                                   float* __restrict__ dinv) {
  __shared__ int s_w[4];
  const int tid = threadIdx.x, lane = tid & 63, wid = tid >> 6;
  const int base = blockIdx.x * 1024 + tid * 4;
  int v0 = 0, v1 = 0, v2 = 0, v3 = 0;
  if (base + 3 < N_NODES) {
    int4 v = *(const int4*)(counts + base);
    v0 = v.x; v1 = v.y; v2 = v.z; v3 = v.w;
  } else if (base < N_NODES) {
    v0 = counts[base];
    if (base + 1 < N_NODES) v1 = counts[base + 1];
    if (base + 2 < N_NODES) v2 = counts[base + 2];
  }
  if (base < N_NODES) {
    dinv[base] = rsqrtf((float)v0 + 1.0f);
    if (base + 1 < N_NODES) dinv[base + 1] = rsqrtf((float)v1 + 1.0f);
    if (base + 2 < N_NODES) dinv[base + 2] = rsqrtf((float)v2 + 1.0f);
    if (base + 3 < N_NODES) dinv[base + 3] = rsqrtf((float)v3 + 1.0f);
  }
  int t = v0 + v1 + v2 + v3;
  int incl = t;
#pragma unroll
  for (int d = 1; d < 64; d <<= 1) {
    int x = __shfl_up(incl, d);
    if (lane >= d) incl += x;
  }
  if (lane == 63) s_w[wid] = incl;
  __syncthreads();
  int woff = 0;
#pragma unroll
  for (int j = 0; j < 4; j++)
    if (j < wid) woff += s_w[j];
  int p = woff + incl - t;
  if (base < N_NODES) offs[base] = p;
  p += v0;
  if (base + 1 < N_NODES) offs[base + 1] = p;
  p += v1;
  if (base + 2 < N_NODES) offs[base + 2] = p;
  p += v2;
  if (base + 3 < N_NODES) offs[base + 3] = p;
  if (tid == 255) bsum[blockIdx.x] = woff + incl;
}

__global__ void scan_tops(int* __restrict__ bsum, int* __restrict__ offs, int nblk) {
  int lane = threadIdx.x;
  int v = (lane < nblk) ? bsum[lane] : 0;
  int incl = v;
#pragma unroll
  for (int d = 1; d < 64; d <<= 1) {
    int x = __shfl_up(incl, d);
    if (lane >= d) incl += x;
  }
  if (lane < nblk) bsum[lane] = incl - v;
  if (lane == 63) offs[N_NODES] = incl;
}

__global__ __launch_bounds__(256) void scan_add(int* __restrict__ offs,
                                                const int* __restrict__ bsum) {
  const int add = bsum[blockIdx.x];
  const int base = blockIdx.x * 1024 + threadIdx.x * 4;
  if (base + 3 < N_NODES) {
    int4 v = *(const int4*)(offs + base);
    v.x += add; v.y += add; v.z += add; v.w += add;
    *(int4*)(offs + base) = v;
  } else if (base < N_NODES) {
    offs[base] += add;
    if (base + 1 < N_NODES) offs[base + 1] += add;
    if (base + 2 < N_NODES) offs[base + 2] += add;
  }
}

// ---------------- merged weight conversion: W[K][N] fp32 -> hi/lo [N][K] bf16 ----------------
__device__ __forceinline__ void wt_one(const float* W, unsigned short* Wh, unsigned short* Wl,
                                       int K, int N, int idx) {
  int k = idx / N, n = idx - k * N;
  unsigned short h, l;
  split2(W[idx], h, l);
  Wh[(size_t)n * K + k] = h;
  Wl[(size_t)n * K + k] = l;
}

__global__ void convert_weights(const float* __restrict__ We1, const float* __restrict__ We2,
                                const float* __restrict__ Wd1, const float* __restrict__ Wd2,
                                unsigned short* W1h, unsigned short* W1l,
                                unsigned short* W2h, unsigned short* W2l,
                                unsigned short* W3h, unsigned short* W3l,
                                unsigned short* W4h, unsigned short* W4l) {
  int idx = blockIdx.x * blockDim.x + threadIdx.x;
  if (idx < 32768) {
    wt_one(We1, W1h, W1l, 256, 128, idx);
  } else if (idx < 40960) {
    wt_one(We2, W2h, W2l, 128, 64, idx - 32768);
  } else if (idx < 49152) {
    wt_one(Wd1, W3h, W3l, 64, 128, idx - 40960);
  } else if (idx < 81920) {
    wt_one(Wd2, W4h, W4l, 128, 256, idx - 49152);
  }
}

// ---------------- split-bf16 MFMA GEMM ----------------
// STATS: per-block stat partials to spart (no global atomics).
// BNIN : A is fp32 pre-BN; apply relu(v*scale+shift) in staging, side-write Aout.
// FILL : blocks >= gemmBX run the CSR fill scatter instead (co-dispatch).
template <int BN, bool STATS, bool AF32, bool BNIN, bool FILL>
__global__ __launch_bounds__(256) void mfma_gemm_split(
    const unsigned short* __restrict__ Ahi, const unsigned short* __restrict__ Alo,
    const float* __restrict__ Af,
    const unsigned short* __restrict__ Whi, const unsigned short* __restrict__ Wlo,
    const float* __restrict__ bias, const float* __restrict__ rowsum,
    unsigned short* __restrict__ Cb, float* __restrict__ Cf,
    float* __restrict__ spart, int M, int K, int N,
    const float* __restrict__ bnstat, const float* __restrict__ bng,
    const float* __restrict__ bnb, float* __restrict__ Aout,
    const int* __restrict__ fsrc, const int* __restrict__ fdst,
    const int* __restrict__ foffs, const int* __restrict__ feslot,
    const float* __restrict__ fdinv, unsigned* __restrict__ fcsr, int fE, int gemmBX) {
  constexpr int BM = 128;
  constexpr int MT = (BN == 128) ? 4 : 2;
  constexpr int NT = 4;
  const int tid = threadIdx.x;
  if (FILL && (int)blockIdx.x >= gemmBX) {
    int idx = ((int)blockIdx.x - gemmBX) * 256 + tid;
    int stride = ((int)gridDim.x - gemmBX) * 256;
    for (int e = idx; e < fE; e += stride) {
      int s = fsrc[e], d = fdst[e];
      int p = foffs[d] + feslot[e];
      unsigned ent = (unsigned)s | ((unsigned)f2h(fdinv[s]) << 16);
      __builtin_nontemporal_store(ent, &fcsr[p]);
    }
    return;
  }
  __shared__ __align__(16) unsigned short AsH[4][BM][8];
  __shared__ __align__(16) unsigned short AsL[4][BM][8];
  __shared__ __align__(16) unsigned short BsH[4][BN][8];
  __shared__ __align__(16) unsigned short BsL[4][BN][8];
  __shared__ float sls[STATS ? BN : 1], slq[STATS ? BN : 1];
  __shared__ float s_bsc[BNIN ? 256 : 1], s_bsh[BNIN ? 256 : 1];
  const int lane = tid & 63, wid = tid >> 6;
  const int quad = lane >> 4, ln = lane & 15;
  const int m0 = blockIdx.x * BM;
  const int n0 = blockIdx.y * BN;
  const int wm = (BN == 128) ? (wid & 1) * 64 : wid * 32;
  const int wn = (BN == 128) ? (wid >> 1) * 64 : 0;
  f32x4 acc[MT][NT] = {};
  if (STATS && tid < BN) {
    sls[tid] = 0.f;
    slq[tid] = 0.f;
  }
  if (BNIN) {
    if (tid < K) {
      const float invN = 1.0f / (float)N_NODES;
      float mean = bnstat[tid] * invN;
      float var = fmaxf(bnstat[256 + tid] * invN - mean * mean, 0.f);
      float inv = rsqrtf(var + BN_EPS);
      float sc = bng[tid] * inv;
      s_bsc[tid] = sc;
      s_bsh[tid] = bnb[tid] - mean * sc;
    }
    __syncthreads();
  }

  const int arow = tid >> 2, aseg = tid & 3;
  for (int k0 = 0; k0 < K; k0 += 32) {
#pragma unroll
    for (int i = 0; i < 2; i++) {
      int row = arow + i * 64;
      int gm = m0 + row;
      if (AF32) {
        float4 u0 = make_float4(0.f, 0.f, 0.f, 0.f), u1 = u0;
        if (gm < M) {
          u0 = *(const float4*)(Af + (size_t)gm * K + k0 + aseg * 8);
          u1 = *(const float4*)(Af + (size_t)gm * K + k0 + aseg * 8 + 4);
          if (BNIN) {
            int c = k0 + aseg * 8;
            u0.x = fmaxf(fmaf(u0.x, s_bsc[c + 0], s_bsh[c + 0]), 0.f);
            u0.y = fmaxf(fmaf(u0.y, s_bsc[c + 1], s_bsh[c + 1]), 0.f);
            u0.z = fmaxf(fmaf(u0.z, s_bsc[c + 2], s_bsh[c + 2]), 0.f);
            u0.w = fmaxf(fmaf(u0.w, s_bsc[c + 3], s_bsh[c + 3]), 0.f);
            u1.x = fmaxf(fmaf(u1.x, s_bsc[c + 4], s_bsh[c + 4]), 0.f);
            u1.y = fmaxf(fmaf(u1.y, s_bsc[c + 5], s_bsh[c + 5]), 0.f);
            u1.z = fmaxf(fmaf(u1.z, s_bsc[c + 6], s_bsh[c + 6]), 0.f);
            u1.w = fmaxf(fmaf(u1.w, s_bsc[c + 7], s_bsh[c + 7]), 0.f);
            *(float4*)(Aout + (size_t)gm * K + c) = u0;
            *(float4*)(Aout + (size_t)gm * K + c + 4) = u1;
          }
        }
        ushort4 h0, l0, h1, l1;
        split2(u0.x, h0.x, l0.x); split2(u0.y, h0.y, l0.y);
        split2(u0.z, h0.z, l0.z); split2(u0.w, h0.w, l0.w);
        split2(u1.x, h1.x, l1.x); split2(u1.y, h1.y, l1.y);
        split2(u1.z, h1.z, l1.z); split2(u1.w, h1.w, l1.w);
        *(ushort4*)(&AsH[aseg][row][0]) = h0;
        *(ushort4*)(&AsH[aseg][row][4]) = h1;
        *(ushort4*)(&AsL[aseg][row][0]) = l0;
        *(ushort4*)(&AsL[aseg][row][4]) = l1;
      } else {
        ushort8v vh = {0, 0, 0, 0, 0, 0, 0, 0};
        ushort8v vl = {0, 0, 0, 0, 0, 0, 0, 0};
        if (gm < M) {
          vh = *(const ushort8v*)(Ahi + (size_t)gm * K + k0 + aseg * 8);
          vl = *(const ushort8v*)(Alo + (size_t)gm * K + k0 + aseg * 8);
        }
        *(ushort8v*)(&AsH[aseg][row][0]) = vh;
        *(ushort8v*)(&AsL[aseg][row][0]) = vl;
      }
    }
#pragma unroll
    for (int i = 0; i < BN / 64; i++) {
      int n = arow + i * 64;
      *(ushort8v*)(&BsH[aseg][n][0]) =
          *(const ushort8v*)(Whi + (size_t)(n0 + n) * K + k0 + aseg * 8);
      *(ushort8v*)(&BsL[aseg][n][0]) =
          *(const ushort8v*)(Wlo + (size_t)(n0 + n) * K + k0 + aseg * 8);
    }
    __syncthreads();
    bf16x8 ah[MT], al[MT], bh[NT], bl[NT];
#pragma unroll
    for (int mt = 0; mt < MT; mt++) {
      ah[mt] = *(const bf16x8*)(&AsH[quad][wm + mt * 16 + ln][0]);
      al[mt] = *(const bf16x8*)(&AsL[quad][wm + mt * 16 + ln][0]);
    }
#pragma unroll
    for (int nt = 0; nt < NT; nt++) {
      bh[nt] = *(const bf16x8*)(&BsH[quad][wn + nt * 16 + ln][0]);
      bl[nt] = *(const bf16x8*)(&BsL[quad][wn + nt * 16 + ln][0]);
    }
#pragma unroll
    for (int mt = 0; mt < MT; mt++)
#pragma unroll
      for (int nt = 0; nt < NT; nt++) {
        acc[mt][nt] = __builtin_amdgcn_mfma_f32_16x16x32_bf16(ah[mt], bl[nt], acc[mt][nt], 0, 0, 0);
        acc[mt][nt] = __builtin_amdgcn_mfma_f32_16x16x32_bf16(al[mt], bh[nt], acc[mt][nt], 0, 0, 0);
        acc[mt][nt] = __builtin_amdgcn_mfma_f32_16x16x32_bf16(ah[mt], bh[nt], acc[mt][nt], 0, 0, 0);
      }
    __syncthreads();
  }

  if (!STATS) {
#pragma unroll
    for (int nt = 0; nt < NT; nt++) {
      int gn = n0 + wn + nt * 16 + ln;
      float bv = bias[gn];
#pragma unroll
      for (int mt = 0; mt < MT; mt++) {
#pragma unroll
        for (int r = 0; r < 4; r++) {
          int gm = m0 + wm + mt * 16 + quad * 4 + r;
          if (gm < M) Cb[(size_t)gm * N + gn] = f2bf(acc[mt][nt][r] + bv);
        }
      }
    }
  } else {
    float rs[MT][4];
#pragma unroll
    for (int mt = 0; mt < MT; mt++)
#pragma unroll
      for (int r = 0; r < 4; r++) {
        int gm = m0 + wm + mt * 16 + quad * 4 + r;
        rs[mt][r] = (gm < M) ? rowsum[gm] : 0.f;
      }
#pragma unroll
    for (int nt = 0; nt < NT; nt++) {
      int gn = n0 + wn + nt * 16 + ln;
      float bv = bias[gn];
      float ls = 0.f, lq = 0.f;
#pragma unroll
      for (int mt = 0; mt < MT; mt++) {
#pragma unroll
        for (int r = 0; r < 4; r++) {
          int gm = m0 + wm + mt * 16 + quad * 4 + r;
          if (gm < M) {
            float v = fmaxf(fmaf(bv, rs[mt][r], acc[mt][nt][r]), 0.f);
            Cf[(size_t)gm * N + gn] = v;
            ls += v;
            lq = fmaf(v, v, lq);
          }
        }
      }
      ls += __shfl_xor(ls, 16); ls += __shfl_xor(ls, 32);
      lq += __shfl_xor(lq, 16); lq += __shfl_xor(lq, 32);
      if (quad == 0) {
        atomicAdd(&sls[wn + nt * 16 + ln], ls);
        atomicAdd(&slq[wn + nt * 16 + ln], lq);
      }
    }
    __syncthreads();
    if (tid < BN) {
      size_t base = (size_t)blockIdx.x * (2 * N);
      spart[base + n0 + tid] = sls[tid];
      spart[base + N + n0 + tid] = slq[tid];
    }
  }
}

// reduce per-block GEMM stat partials: stat[c] = sum_bx spart[bx][c]
__global__ __launch_bounds__(256) void reduce_stats(const float* __restrict__ spart,
                                                    float* __restrict__ stat, int nbx, int N) {
  const int c = blockIdx.x;
  const int t = threadIdx.x;
  const int N2 = 2 * N;
  float ls = 0.f, lq = 0.f;
  for (int b = t; b < nbx; b += 256) {
    ls += spart[(size_t)b * N2 + c];
    lq += spart[(size_t)b * N2 + N + c];
  }
#pragma unroll
  for (int d = 1; d < 64; d <<= 1) {
    ls += __shfl_xor(ls, d);
    lq += __shfl_xor(lq, d);
  }
  __shared__ float rl[4], rq[4];
  if ((t & 63) == 0) {
    rl[t >> 6] = ls;
    rq[t >> 6] = lq;
  }
  __syncthreads();
  if (t == 0) {
    stat[c] = rl[0] + rl[1] + rl[2] + rl[3];
    stat[256 + c] = rq[0] + rq[1] + rq[2] + rq[3];
  }
}

// ---------------- agg F=128, packed-u32 readlane broadcast, one node per wave ----------------
// ROWSUM: blocks >= aggBX run compute_rowsum (co-dispatch).
template <bool RELU_STATS, bool OUT_SPLIT, bool ROWSUM>
__global__ __launch_bounds__(256) void agg128_rl(
    const unsigned short* __restrict__ hb, const int* __restrict__ offs,
    const unsigned* __restrict__ csrU, const float* __restrict__ dinv,
    float* __restrict__ outf, unsigned short* __restrict__ outhi,
    unsigned short* __restrict__ outlo, float* __restrict__ stat,
    float* __restrict__ rowsum_out, int aggBX) {
  const int tid = threadIdx.x;
  if (ROWSUM && (int)blockIdx.x >= aggBX) {
    int i = ((int)blockIdx.x - aggBX) * 256 + tid;
    int stride = ((int)gridDim.x - aggBX) * 256;
    for (; i < N_NODES; i += stride) {
      float di = dinv[i];
      float s = di;
      int e1 = offs[i + 1];
      for (int e = offs[i]; e < e1; e++) s += h2f((unsigned short)(csrU[e] >> 16));
      rowsum_out[i] = di * s;
    }
    return;
  }
  const int lane = tid & 63;
  const int widx = tid >> 6;
  const int nwaves = aggBX * 4;
  float ls0 = 0.f, ls1 = 0.f, lq0 = 0.f, lq1 = 0.f;

  for (int node = blockIdx.x * 4 + widx; node < N_NODES; node += nwaves) {
    const int e0 = __builtin_amdgcn_readfirstlane(offs[node]);
    const int e1 = __builtin_amdgcn_readfirstlane(offs[node + 1]);
    float a0 = 0.f, a1 = 0.f;
    for (int e = e0; e < e1; e += 64) {
      const int cnt = min(64, e1 - e);
      unsigned ent = 0;
      if (lane < cnt) ent = csrU[e + lane];
      const int nb = (cnt + 7) & ~7;
      for (int j = 0; j < nb; j += 8) {
#pragma unroll
        for (int u = 0; u < 8; u++) {
          unsigned ce = (unsigned)rdl((int)ent, j + u);
          int s = (int)(ce & 0xFFFFu);
          float w = h2f((unsigned short)(ce >> 16));
          unsigned v = *(const unsigned*)(hb + (size_t)s * 128 + lane * 2);
          a0 = fmaf(bflo(v), w, a0);
          a1 = fmaf(bfhi(v), w, a1);
        }
      }
    }
    float di = dinv[node];
    unsigned vs = *(const unsigned*)(hb + (size_t)node * 128 + lane * 2);
    a0 = fmaf(bflo(vs), di, a0) * di;
    a1 = fmaf(bfhi(vs), di, a1) * di;
    if (RELU_STATS) {
      a0 = fmaxf(a0, 0.f);
      a1 = fmaxf(a1, 0.f);
      ls0 += a0; ls1 += a1;
      lq0 = fmaf(a0, a0, lq0);
      lq1 = fmaf(a1, a1, lq1);
    }
    if (OUT_SPLIT) {
      unsigned short h0, l0, h1, l1;
      split2(a0, h0, l0);
      split2(a1, h1, l1);
      *(unsigned*)(outhi + (size_t)node * 128 + lane * 2) = (unsigned)h0 | ((unsigned)h1 << 16);
      *(unsigned*)(outlo + (size_t)node * 128 + lane * 2) = (unsigned)l0 | ((unsigned)l1 << 16);
    } else {
      *(float2*)(outf + (size_t)node * 128 + lane * 2) = make_float2(a0, a1);
    }
  }

  if (RELU_STATS) {
    __shared__ float red[4][128];
    red[widx][lane * 2 + 0] = ls0;
    red[widx][lane * 2 + 1] = ls1;
    __syncthreads();
    if (tid < 128) {
      atomicAdd(&stat[tid], red[0][tid] + red[1][tid] + red[2][tid] + red[3][tid]);
    }
    __syncthreads();
    red[widx][lane * 2 + 0] = lq0;
    red[widx][lane * 2 + 1] = lq1;
    __syncthreads();
    if (tid < 128) {
      atomicAdd(&stat[256 + tid], red[0][tid] + red[1][tid] + red[2][tid] + red[3][tid]);
    }
  }
}

// ---------------- agg F=64, packed-u32 readlane broadcast, two edges per gather ----------------
template <bool RELU_STATS, bool OUT_SPLIT>
__global__ __launch_bounds__(256) void agg64_rl(
    const unsigned short* __restrict__ hb, const int* __restrict__ offs,
    const unsigned* __restrict__ csrU, const float* __restrict__ dinv,
    float* __restrict__ outf, unsigned short* __restrict__ outhi,
    unsigned short* __restrict__ outlo, float* __restrict__ stat) {
  const int tid = threadIdx.x;
  const int lane = tid & 63;
  const int widx = tid >> 6;
  const int half = lane >> 5;
  const int hl = lane & 31;
  const int nwaves = gridDim.x * 4;
  float ls0 = 0.f, ls1 = 0.f, lq0 = 0.f, lq1 = 0.f;

  for (int node = blockIdx.x * 4 + widx; node < N_NODES; node += nwaves) {
    const int e0 = __builtin_amdgcn_readfirstlane(offs[node]);
    const int e1 = __builtin_amdgcn_readfirstlane(offs[node + 1]);
    float a0 = 0.f, a1 = 0.f;
    for (int e = e0; e < e1; e += 64) {
      const int cnt = min(64, e1 - e);
      unsigned ent = 0;
      if (lane < cnt) ent = csrU[e + lane];
      const int nb = (cnt + 15) & ~15;
      for (int j = 0; j < nb; j += 16) {
#pragma unroll
        for (int u = 0; u < 8; u++) {
          unsigned ca = (unsigned)rdl((int)ent, j + 2 * u);
          unsigned cb = (unsigned)rdl((int)ent, j + 2 * u + 1);
          unsigned ce = half ? cb : ca;
          int s = (int)(ce & 0xFFFFu);
          float w = h2f((unsigned short)(ce >> 16));
          unsigned v = *(const unsigned*)(hb + (size_t)s * 64 + hl * 2);
          a0 = fmaf(bflo(v), w, a0);
          a1 = fmaf(bfhi(v), w, a1);
        }
      }
    }
    a0 += __shfl_xor(a0, 32);
    a1 += __shfl_xor(a1, 32);
    float di = dinv[node];
    unsigned vs = *(const unsigned*)(hb + (size_t)node * 64 + hl * 2);
    a0 = fmaf(bflo(vs), di, a0) * di;
    a1 = fmaf(bfhi(vs), di, a1) * di;
    if (RELU_STATS) {
      a0 = fmaxf(a0, 0.f);
      a1 = fmaxf(a1, 0.f);
      if (half == 0) {
        ls0 += a0; ls1 += a1;
        lq0 = fmaf(a0, a0, lq0);
        lq1 = fmaf(a1, a1, lq1);
      }
    }
    if (half == 0) {
      if (OUT_SPLIT) {
        unsigned short h0, l0, h1, l1;
        split2(a0, h0, l0);
        split2(a1, h1, l1);
        *(unsigned*)(outhi + (size_t)node * 64 + hl * 2) = (unsigned)h0 | ((unsigned)h1 << 16);
        *(unsigned*)(outlo + (size_t)node * 64 + hl * 2) = (unsigned)l0 | ((unsigned)l1 << 16);
      } else {
        *(float2*)(outf + (size_t)node * 64 + hl * 2) = make_float2(a0, a1);
      }
    }
  }

  if (RELU_STATS) {
    __shared__ float red[4][64];
    if (half == 0) {
      red[widx][hl * 2 + 0] = ls0;
      red[widx][hl * 2 + 1] = ls1;
    }
    __syncthreads();
    if (tid < 64) {
      atomicAdd(&stat[tid], red[0][tid] + red[1][tid] + red[2][tid] + red[3][tid]);
    }
    __syncthreads();
    if (half == 0) {
      red[widx][hl * 2 + 0] = lq0;
      red[widx][hl * 2 + 1] = lq1;
    }
    __syncthreads();
    if (tid < 64) {
      atomicAdd(&stat[256 + tid], red[0][tid] + red[1][tid] + red[2][tid] + red[3][tid]);
    }
  }
}

// ---------------- BN apply with inline finalize ----------------
template <int F, bool RELU, bool WF32, bool WB16, bool WSPLIT>
__global__ __launch_bounds__(256) void bn_apply_f(const float* __restrict__ a,
                                                  const float* __restrict__ stat,
                                                  const float* __restrict__ g,
                                                  const float* __restrict__ bb,
                                                  float* __restrict__ outf,
                                                  unsigned short* __restrict__ outb,
                                                  unsigned short* __restrict__ outhi,
                                                  unsigned short* __restrict__ outlo) {
  __shared__ float s_scale[F], s_shift[F];
  const int tid = threadIdx.x;
  if (tid < F) {
    const float invN = 1.0f / (float)N_NODES;
    float mean = stat[tid] * invN;
    float var = fmaxf(stat[256 + tid] * invN - mean * mean, 0.f);
    float inv = rsqrtf(var + BN_EPS);
    float sc = g[tid] * inv;
    s_scale[tid] = sc;
    s_shift[tid] = bb[tid] - mean * sc;
  }
  __syncthreads();
  constexpr int C4 = F / 4;
  const int total = N_NODES * C4;
  for (int idx = blockIdx.x * blockDim.x + tid; idx < total; idx += gridDim.x * blockDim.x) {
    int c4 = idx % C4;
    float4 v = ((const float4*)a)[idx];
    float4 s = *(float4*)&s_scale[c4 * 4];
    float4 sh = *(float4*)&s_shift[c4 * 4];
    float4 o;
    o.x = fmaf(v.x, s.x, sh.x);
    o.y = fmaf(v.y, s.y, sh.y);
    o.z = fmaf(v.z, s.z, sh.z);
    o.w = fmaf(v.w, s.w, sh.w);
    if (RELU) {
      o.x = fmaxf(o.x, 0.f);
      o.y = fmaxf(o.y, 0.f);
      o.z = fmaxf(o.z, 0.f);
      o.w = fmaxf(o.w, 0.f);
    }
    if (WF32) ((float4*)outf)[idx] = o;
    if (WB16) {
      ushort4 b;
      b.x = f2bf(o.x); b.y = f2bf(o.y); b.z = f2bf(o.z); b.w = f2bf(o.w);
      ((ushort4*)outb)[idx] = b;
    }
    if (WSPLIT) {
      ushort4 h, l;
      split2(o.x, h.x, l.x);
      split2(o.y, h.y, l.y);
      split2(o.z, h.z, l.z);
      split2(o.w, h.w, l.w);
      ((ushort4*)outhi)[idx] = h;
      ((ushort4*)outlo)[idx] = l;
    }
  }
}

extern "C" void kernel_launch(void* const* d_in, const int* in_sizes, int n_in,
                              void* d_out, int out_size, void* d_ws, size_t ws_size,
                              hipStream_t stream) {
  const float* x = (const float*)d_in[0];
  const int* ei = (const int*)d_in[1];
  const int E = in_sizes[1] / 2;
  const int* src = ei;
  const int* dst = ei + E;
  const float* We1 = (const float*)d_in[2];  const float* be1 = (const float*)d_in[3];
  const float* g1  = (const float*)d_in[4];  const float* bb1 = (const float*)d_in[5];
  const float* We2 = (const float*)d_in[6];  const float* be2 = (const float*)d_in[7];
  const float* g2  = (const float*)d_in[8];  const float* bb2 = (const float*)d_in[9];
  const float* Wd1 = (const float*)d_in[10]; const float* bd1 = (const float*)d_in[11];
  const float* g3  = (const float*)d_in[12]; const float* bb3 = (const float*)d_in[13];
  const float* Wd2 = (const float*)d_in[14]; const float* bd2 = (const float*)d_in[15];
  const float* g4  = (const float*)d_in[16]; const float* bb4 = (const float*)d_in[17];

  float* out = (float*)d_out;
  char* ws = (char*)d_ws;
  unsigned short* A0b  = (unsigned short*)(ws + 0);
  unsigned short* A1b  = (unsigned short*)(ws + 12800000);
  unsigned short* C2b  = (unsigned short*)(ws + 32000000);
  unsigned short* G3hi = (unsigned short*)(ws + 0);
  unsigned short* G3lo = (unsigned short*)(ws + 6400000);
  unsigned short* D3b  = (unsigned short*)(ws + 12800000);
  unsigned short* G4hi = (unsigned short*)(ws + 0);
  unsigned short* G4lo = (unsigned short*)(ws + 25600000);
  unsigned short* Wb   = (unsigned short*)(ws + 48000000);
  unsigned short* W1h = Wb;            unsigned short* W1l = W1h + 32768;
  unsigned short* W2h = W1l + 32768;   unsigned short* W2l = W2h + 8192;
  unsigned short* W3h = W2l + 8192;    unsigned short* W3l = W3h + 8192;
  unsigned short* W4h = W3l + 8192;    unsigned short* W4l = W4h + 32768;
  float* B0f  = (float*)(ws + 51200000);
  int*   eslot  = (int*)(ws + 51200000);     // dead before first B0f write (agg L1)
  unsigned* csrU = (unsigned*)(ws + 102400000);
  float* spart  = (float*)(ws + 105600000);  // 391 x 512 floats
  float* stat4  = (float*)(ws + 108800000);
  int*   bsum   = (int*)(ws + 108808192);
  int*   counts = (int*)(ws + 108810000);    // reused as rowsum after scan_blocks
  int*   offs   = (int*)(ws + 109210000);
  float* dinv   = (float*)(ws + 109410064);
  if (ws_size < 109604160) return;
  float* rowsum = (float*)counts;

  float* enc1 = out + (size_t)N_NODES * F0;
  float* enc2 = enc1 + (size_t)N_NODES * F1;

  const int EB = (E + 255) / 256;
  const int AGG_GRID = 2048;
  const int MB = (N_NODES + 127) / 128;        // 391
  const int SCAN_B = (N_NODES + 1023) / 1024;  // 49
  const int FB = 512;   // fill blocks co-dispatched with GEMM L1
  const int RB = 196;   // rowsum blocks co-dispatched with agg L1

  convert_weights<<<320, 256, 0, stream>>>(We1, We2, Wd1, Wd2, W1h, W1l, W2h, W2l,
                                           W3h, W3l, W4h, W4l);
  hipMemsetAsync(counts, 0, N_NODES * sizeof(int), stream);
  hipMemsetAsync(stat4, 0, 4 * 512 * sizeof(float), stream);
  count_dst<<<EB, 256, 0, stream>>>(dst, counts, eslot, E);
  scan_blocks<<<SCAN_B, 256, 0, stream>>>(counts, offs, bsum, dinv);
  scan_tops<<<1, 64, 0, stream>>>(bsum, offs, SCAN_B);
  scan_add<<<SCAN_B, 256, 0, stream>>>(offs, bsum);

  // ---- Layer 1: GEMM L1 co-dispatched with CSR fill ----
  mfma_gemm_split<128, false, true, false, true><<<dim3(MB + FB, 1), 256, 0, stream>>>(
      nullptr, nullptr, x, W1h, W1l, be1, nullptr, A0b, nullptr, nullptr, N_NODES, F0, F1,
      nullptr, nullptr, nullptr, nullptr,
      src, dst, offs, eslot, dinv, csrU, E, MB);
  // agg L1 co-dispatched with rowsum
  agg128_rl<true, false, true><<<AGG_GRID + RB, 256, 0, stream>>>(
      A0b, offs, csrU, dinv, B0f, nullptr, nullptr, stat4, rowsum, AGG_GRID);

  // ---- Layer 2: GEMM L2 with fused BN1 (reads B0f, side-writes enc1) ----
  mfma_gemm_split<64, false, true, true, false><<<dim3(MB, 1), 256, 0, stream>>>(
      nullptr, nullptr, B0f, W2h, W2l, be2, nullptr, A1b, nullptr, nullptr, N_NODES, F1, F2,
      stat4, g1, bb1, enc1,
      nullptr, nullptr, nullptr, nullptr, nullptr, nullptr, 0, 0);
  agg64_rl<true, false><<<AGG_GRID, 256, 0, stream>>>(
      A1b, offs, csrU, dinv, B0f, nullptr, nullptr, stat4 + 512);
  bn_apply_f<F2, false, true, true, false><<<2048, 256, 0, stream>>>(
      B0f, stat4 + 512, g2, bb2, enc2, C2b, nullptr, nullptr);

  // ---- Layer 3: F2 -> F1 (propagate FIRST) ----
  agg64_rl<false, true><<<AGG_GRID, 256, 0, stream>>>(
      C2b, offs, csrU, dinv, nullptr, G3hi, G3lo, nullptr);
  mfma_gemm_split<128, true, false, false, false><<<dim3(MB, 1), 256, 0, stream>>>(
      G3hi, G3lo, nullptr, W3h, W3l, bd1, rowsum, nullptr, B0f, spart, N_NODES, F2, F1,
      nullptr, nullptr, nullptr, nullptr,
      nullptr, nullptr, nullptr, nullptr, nullptr, nullptr, 0, 0);
  reduce_stats<<<F1, 256, 0, stream>>>(spart, stat4 + 1024, MB, F1);
  bn_apply_f<F1, true, false, true, false><<<2048, 256, 0, stream>>>(
      B0f, stat4 + 1024, g3, bb3, nullptr, D3b, nullptr, nullptr);

  // ---- Layer 4: F1 -> F0 (propagate FIRST) ----
  agg128_rl<false, true, false><<<AGG_GRID, 256, 0, stream>>>(
      D3b, offs, csrU, dinv, nullptr, G4hi, G4lo, nullptr, nullptr, AGG_GRID);
  mfma_gemm_split<128, true, false, false, false><<<dim3(MB, 2), 256, 0, stream>>>(
      G4hi, G4lo, nullptr, W4h, W4l, bd2, rowsum, nullptr, B0f, spart, N_NODES, F1, F0,
      nullptr, nullptr, nullptr, nullptr,
      nullptr, nullptr, nullptr, nullptr, nullptr, nullptr, 0, 0);
  reduce_stats<<<F0, 256, 0, stream>>>(spart, stat4 + 1536, MB, F0);
  bn_apply_f<F0, false, true, false, false><<<2048, 256, 0, stream>>>(
      B0f, stat4 + 1536, g4, bb4, out, nullptr, nullptr, nullptr);
}